// Round 28
// baseline (453.819 us; speedup 1.0000x reference)
//
#include <hip/hip_runtime.h>

#define EPSBN 1e-5f
#define NB 512            // buckets (dst >> 9), 512 nodes per bucket
#define GB 256            // blocks for cnt/reorder tiles
#define CAP 18000         // LDS sort buffer capacity (edges)

typedef float vf4 __attribute__((ext_vector_type(4)));
typedef _Float16 vh8 __attribute__((ext_vector_type(8)));
typedef _Float16 vh4 __attribute__((ext_vector_type(4)));
typedef unsigned int uint32;

// fast tanh: 1 - 2*rcp(exp(2x)+1)
__device__ __forceinline__ float ftanh(float x) {
    float e = __expf(2.0f * x);
    return 1.0f - 2.0f * __builtin_amdgcn_rcpf(e + 1.0f);
}

__device__ __forceinline__ float wave_sum(float v) {
#pragma unroll
    for (int off = 32; off > 0; off >>= 1) v += __shfl_down(v, off);
    return v;
}

__device__ __forceinline__ void z1_of(const float4 hi, const float4 hj,
                                      const float* __restrict__ w, const float* __restrict__ b,
                                      float* z) {
#pragma unroll
    for (int j = 0; j < 8; ++j) {
        z[j] = b[j]
             + hi.x * w[0 * 8 + j] + hi.y * w[1 * 8 + j] + hi.z * w[2 * 8 + j] + hi.w * w[3 * 8 + j]
             + hj.x * w[4 * 8 + j] + hj.y * w[5 * 8 + j] + hj.z * w[6 * 8 + j] + hj.w * w[7 * 8 + j];
    }
}

__device__ __forceinline__ void mat8x4(const float* u, const float* w,
                                       const float* b, float* z) {
#pragma unroll
    for (int c = 0; c < 4; ++c) {
        float t = b[c];
#pragma unroll
        for (int k = 0; k < 8; ++k) t += u[k] * w[k * 4 + c];
        z[c] = t;
    }
}

__device__ __forceinline__ void mat8x8(const float* u, const float* __restrict__ w,
                                       const float* __restrict__ b, float* z) {
#pragma unroll
    for (int j = 0; j < 8; ++j) {
        float t = b[j];
#pragma unroll
        for (int k = 0; k < 8; ++k) t += u[k] * w[k * 8 + j];
        z[j] = t;
    }
}

// block reduction: NV partials per thread, NW waves per block
template <int NV, int NW>
__device__ __forceinline__ void block_reduce_atomics(float* a, float* __restrict__ sums) {
    __shared__ float red[NV * NW];
    int wid = threadIdx.x >> 6, lane = threadIdx.x & 63;
#pragma unroll
    for (int i = 0; i < NV; ++i) {
        float v = wave_sum(a[i]);
        if (lane == 0) red[i * NW + wid] = v;
    }
    __syncthreads();
    if (threadIdx.x < NV) {
        float v = 0.f;
#pragma unroll
        for (int k = 0; k < NW; ++k) v += red[threadIdx.x * NW + k];
        atomicAdd(&sums[threadIdx.x], v);
    }
}

// compute BN scale/shift into LDS from raw sums (all threads; syncs inside)
__device__ __forceinline__ void fin_lds(const float* __restrict__ sums,
                                        const float* __restrict__ g, const float* __restrict__ be,
                                        int d, float inv, float* out) {
    int j = threadIdx.x;
    if (j < d) {
        float mu = sums[j] * inv;
        float var = sums[d + j] * inv - mu * mu;
        float s = g[j] * rsqrtf(var + EPSBN);
        out[j] = s;
        out[d + j] = be[j] - mu * s;
    }
    __syncthreads();
}

// per-edge z1-stats accumulate (h-based)
__device__ __forceinline__ void stats1_edge(float4 hi, float4 hj,
                                            const float* __restrict__ w1, const float* __restrict__ b1,
                                            float* a) {
    float z[8];
    z1_of(hi, hj, w1, b1, z);
#pragma unroll
    for (int j = 0; j < 8; ++j) { a[j] += z[j]; a[8 + j] += z[j] * z[j]; }
}

// h-based z2 (fallback only)
__device__ __forceinline__ vf4 z2_edge(float4 hi, float4 hj,
                                       const float* __restrict__ w1, const float* __restrict__ b1,
                                       const float* ss1,
                                       const float* __restrict__ w2, const float* __restrict__ b2) {
    float z[8], m1[8], z2[4];
    z1_of(hi, hj, w1, b1, z);
#pragma unroll
    for (int j = 0; j < 8; ++j) m1[j] = ftanh(z[j] * ss1[j] + ss1[8 + j]);
    mat8x4(m1, w2, b2, z2);
    vf4 r = {z2[0], z2[1], z2[2], z2[3]};
    return r;
}

__device__ __forceinline__ void stats2_edge(float4 hi, float4 hj,
                                            const float* __restrict__ w1, const float* __restrict__ b1,
                                            const float* ss1,
                                            const float* __restrict__ w2, const float* __restrict__ b2,
                                            float* a) {
    vf4 q = z2_edge(hi, hj, w1, b1, ss1, w2, b2);
    a[0] += q.x; a[4] += q.x * q.x;
    a[1] += q.y; a[5] += q.y * q.y;
    a[2] += q.z; a[6] += q.z * q.z;
    a[3] += q.w; a[7] += q.w * q.w;
}

// ---------------- node input projection ----------------
__global__ __launch_bounds__(256) void k_h(const float* __restrict__ pos, const float* __restrict__ vel,
                                           const float* __restrict__ w, const float* __restrict__ b,
                                           float4* __restrict__ h, int n) {
    int i = blockIdx.x * blockDim.x + threadIdx.x;
    if (i >= n) return;
    float2 p = ((const float2*)pos)[i];
    float2 v = ((const float2*)vel)[i];
    float o[4];
#pragma unroll
    for (int d = 0; d < 4; ++d)
        o[d] = b[d] + p.x * w[0 * 4 + d] + p.y * w[1 * 4 + d] + v.x * w[2 * 4 + d] + v.y * w[3 * 4 + d];
    h[i] = make_float4(o[0], o[1], o[2], o[3]);
}

// ---------------- z-tables: ziR = Wi^T h (fp32), zjR = Wj^T h + b1 (fp16) ----------------
__global__ __launch_bounds__(256) void k_zt(const float4* __restrict__ h,
                                            const float* __restrict__ w1, const float* __restrict__ b1,
                                            vf4* __restrict__ zi, vh8* __restrict__ zjH, int n) {
    int i = blockIdx.x * blockDim.x + threadIdx.x;
    if (i >= n) return;
    float4 hv = h[i];
    float zi8[8];
    vh8 hpk;
#pragma unroll
    for (int j = 0; j < 8; ++j) {
        zi8[j] = hv.x * w1[0 * 8 + j] + hv.y * w1[1 * 8 + j] + hv.z * w1[2 * 8 + j] + hv.w * w1[3 * 8 + j];
        float zj = b1[j]
                 + hv.x * w1[4 * 8 + j] + hv.y * w1[5 * 8 + j] + hv.z * w1[6 * 8 + j] + hv.w * w1[7 * 8 + j];
        hpk[j] = (_Float16)zj;
    }
    vf4 a = {zi8[0], zi8[1], zi8[2], zi8[3]};
    vf4 b_ = {zi8[4], zi8[5], zi8[6], zi8[7]};
    zi[2 * (size_t)i] = a; zi[2 * (size_t)i + 1] = b_;
    zjH[i] = hpk;
}

// ---------------- count + fused h-based z1 stats, 1024-thread blocks ----------------
__global__ __launch_bounds__(1024, 1) void k_cnt(const int* __restrict__ idx, const float4* __restrict__ h,
                                                 const float* __restrict__ w1, const float* __restrict__ b1,
                                                 uint32* __restrict__ cntmat, float* __restrict__ sums,
                                                 int E_, int T) {
    __shared__ uint32 hist[NB];
    for (int b = threadIdx.x; b < NB; b += 1024) hist[b] = 0;
    float a[16];
#pragma unroll
    for (int i = 0; i < 16; ++i) a[i] = 0.f;
    __syncthreads();
    int lo = blockIdx.x * T, hi2 = min(E_, lo + T);
    for (int e0 = lo + 4 * threadIdx.x; e0 < hi2; e0 += 4096) {
        int m = min(4, hi2 - e0);
        if (m == 4) {
            int s0 = __builtin_nontemporal_load(idx + e0);
            int s1 = __builtin_nontemporal_load(idx + e0 + 1);
            int s2 = __builtin_nontemporal_load(idx + e0 + 2);
            int s3 = __builtin_nontemporal_load(idx + e0 + 3);
            int d0 = __builtin_nontemporal_load(idx + E_ + e0);
            int d1 = __builtin_nontemporal_load(idx + E_ + e0 + 1);
            int d2 = __builtin_nontemporal_load(idx + E_ + e0 + 2);
            int d3 = __builtin_nontemporal_load(idx + E_ + e0 + 3);
            float4 hi0 = h[d0], hj0 = h[s0];
            float4 hi1 = h[d1], hj1 = h[s1];
            float4 hi2 = h[d2], hj2 = h[s2];
            float4 hi3 = h[d3], hj3 = h[s3];
            atomicAdd(&hist[d0 >> 9], 1u);
            atomicAdd(&hist[d1 >> 9], 1u);
            atomicAdd(&hist[d2 >> 9], 1u);
            atomicAdd(&hist[d3 >> 9], 1u);
            stats1_edge(hi0, hj0, w1, b1, a);
            stats1_edge(hi1, hj1, w1, b1, a);
            stats1_edge(hi2, hj2, w1, b1, a);
            stats1_edge(hi3, hj3, w1, b1, a);
        } else {
            for (int k = 0; k < m; ++k) {
                int s = __builtin_nontemporal_load(idx + e0 + k);
                int d = __builtin_nontemporal_load(idx + E_ + e0 + k);
                float4 hi = h[d], hj = h[s];
                atomicAdd(&hist[d >> 9], 1u);
                stats1_edge(hi, hj, w1, b1, a);
            }
        }
    }
    __syncthreads();
    for (int b = threadIdx.x; b < NB; b += 1024)
        cntmat[(size_t)b * GB + blockIdx.x] = hist[b];
    block_reduce_atomics<16, 16>(a, sums);
}

// block-scan of 256 uints (1/thread), exclusive
__device__ __forceinline__ void scan256(uint32 v, uint32* excl_out, uint32* total) {
    __shared__ uint32 ts[256];
    ts[threadIdx.x] = v;
    __syncthreads();
    for (int off = 1; off < 256; off <<= 1) {
        uint32 t = (threadIdx.x >= (uint32)off) ? ts[threadIdx.x - off] : 0u;
        __syncthreads();
        ts[threadIdx.x] += t;
        __syncthreads();
    }
    *excl_out = ts[threadIdx.x] - v;
    *total = ts[255];
}

// block-scan of 512 uints (2/thread), exclusive
__device__ __forceinline__ void scan512(uint32* v, uint32* excl_out, uint32* total) {
    __shared__ uint32 ts[256];
    uint32 local = v[0] + v[1];
    ts[threadIdx.x] = local;
    __syncthreads();
    for (int off = 1; off < 256; off <<= 1) {
        uint32 t = (threadIdx.x >= (uint32)off) ? ts[threadIdx.x - off] : 0u;
        __syncthreads();
        ts[threadIdx.x] += t;
        __syncthreads();
    }
    *excl_out = ts[threadIdx.x] - local;
    *total = ts[255];
}

__global__ __launch_bounds__(256) void k_scanA(uint32* __restrict__ cntmat, uint32* __restrict__ rowtot) {
    size_t base = (size_t)blockIdx.x * GB + threadIdx.x;
    uint32 v = cntmat[base];
    uint32 excl, tot;
    scan256(v, &excl, &tot);
    cntmat[base] = excl;
    if (threadIdx.x == 0) rowtot[blockIdx.x] = tot;
}

__global__ __launch_bounds__(256) void k_scanB(const uint32* __restrict__ rowtot, uint32* __restrict__ bbase) {
    uint32 v[2];
    v[0] = rowtot[threadIdx.x * 2]; v[1] = rowtot[threadIdx.x * 2 + 1];
    uint32 excl, tot;
    scan512(v, &excl, &tot);
    bbase[threadIdx.x * 2] = excl;
    bbase[threadIdx.x * 2 + 1] = excl + v[0];
    if (threadIdx.x == 0) bbase[NB] = tot;
}

// ---------------- reorder: packed 4B scatter, 1024-thread blocks ----------------
__global__ __launch_bounds__(1024, 1) void k_reorder(const int* __restrict__ idx,
                                                     const uint32* __restrict__ cntmat, const uint32* __restrict__ bbase,
                                                     uint32* __restrict__ sp, int E_, int T) {
    __shared__ uint32 cur[NB];
    for (int b = threadIdx.x; b < NB; b += 1024)
        cur[b] = bbase[b] + cntmat[(size_t)b * GB + blockIdx.x];
    __syncthreads();
    int lo = blockIdx.x * T, hi2 = min(E_, lo + T);
    for (int e0 = lo + 4 * threadIdx.x; e0 < hi2; e0 += 4096) {
        int m = min(4, hi2 - e0);
        if (m == 4) {
            int s0 = __builtin_nontemporal_load(idx + e0);
            int s1 = __builtin_nontemporal_load(idx + e0 + 1);
            int s2 = __builtin_nontemporal_load(idx + e0 + 2);
            int s3 = __builtin_nontemporal_load(idx + e0 + 3);
            int d0 = __builtin_nontemporal_load(idx + E_ + e0);
            int d1 = __builtin_nontemporal_load(idx + E_ + e0 + 1);
            int d2 = __builtin_nontemporal_load(idx + E_ + e0 + 2);
            int d3 = __builtin_nontemporal_load(idx + E_ + e0 + 3);
            uint32 p0 = atomicAdd(&cur[d0 >> 9], 1u);
            uint32 p1 = atomicAdd(&cur[d1 >> 9], 1u);
            uint32 p2 = atomicAdd(&cur[d2 >> 9], 1u);
            uint32 p3 = atomicAdd(&cur[d3 >> 9], 1u);
            sp[p0] = ((uint32)(d0 & 511) << 23) | (uint32)s0;
            sp[p1] = ((uint32)(d1 & 511) << 23) | (uint32)s1;
            sp[p2] = ((uint32)(d2 & 511) << 23) | (uint32)s2;
            sp[p3] = ((uint32)(d3 & 511) << 23) | (uint32)s3;
        } else {
            for (int k = 0; k < m; ++k) {
                int s = __builtin_nontemporal_load(idx + e0 + k);
                int d = __builtin_nontemporal_load(idx + E_ + e0 + k);
                uint32 pos = atomicAdd(&cur[d >> 9], 1u);
                sp[pos] = ((uint32)(d & 511) << 23) | (uint32)s;
            }
        }
    }
}

// ---------------- sort2: per-bucket counting sort staged in LDS -> CSR ----------------
__global__ __launch_bounds__(256) void k_sort2(const uint32* __restrict__ sp,
                                               const uint32* __restrict__ bbase, const uint32* __restrict__ rowtot,
                                               int* __restrict__ src2, uint32* __restrict__ nodeoff, int n) {
    extern __shared__ uint32 buf[];
    __shared__ uint32 hist[512];
    __shared__ uint32 cur[512];
    int b = blockIdx.x;
    uint32 start = bbase[b];
    uint32 len = rowtot[b];
    uint32 end = start + len;
    hist[threadIdx.x] = 0;
    hist[threadIdx.x + 256] = 0;
    __syncthreads();
    for (uint32 e = start + threadIdx.x; e < end; e += 256) {
        uint32 pk = __builtin_nontemporal_load(&sp[e]);
        atomicAdd(&hist[pk >> 23], 1u);
    }
    __syncthreads();
    uint32 vv[2];
    vv[0] = hist[2 * threadIdx.x];
    vv[1] = hist[2 * threadIdx.x + 1];
    uint32 excl, tot;
    scan512(vv, &excl, &tot);
    cur[2 * threadIdx.x] = excl;
    cur[2 * threadIdx.x + 1] = excl + vv[0];
    int nodebase = b << 9;
    int node0 = nodebase + 2 * threadIdx.x;
    if (node0 <= n)     nodeoff[node0] = start + excl;
    if (node0 + 1 <= n) nodeoff[node0 + 1] = start + excl + vv[0];
    __syncthreads();
    for (uint32 e = start + threadIdx.x; e < end; e += 256) {
        uint32 pk = __builtin_nontemporal_load(&sp[e]);
        uint32 pos = atomicAdd(&cur[pk >> 23], 1u);
        uint32 src = pk & 0x7FFFFFu;
        if (pos < (uint32)CAP) buf[pos] = src;
        else __builtin_nontemporal_store((int)src, &src2[start + pos]);
    }
    __syncthreads();
    uint32 lim = min(len, (uint32)CAP);
    for (uint32 k = threadIdx.x; k < lim; k += 256)
        __builtin_nontemporal_store((int)buf[k], &src2[start + k]);
}

// ---------------- finalize BN stats -> scale/shift ----------------
__global__ void k_fin(const float* __restrict__ sums, float* __restrict__ ss,
                      const float* __restrict__ g, const float* __restrict__ be,
                      int d, float inv_count) {
    int j = threadIdx.x;
    if (j >= d) return;
    float mu = sums[j] * inv_count;
    float var = sums[d + j] * inv_count - mu * mu;
    float s = g[j] * rsqrtf(var + EPSBN);
    ss[j] = s;
    ss[d + j] = be[j] - mu * s;
}

// ---------------- fold BN1 into zi (zi_f = s * ziR + t) ----------------
__global__ __launch_bounds__(256) void k_fold(vf4* __restrict__ zi, const float* __restrict__ ss1g, int n) {
    __shared__ float s[16];
    if (threadIdx.x < 16) s[threadIdx.x] = ss1g[threadIdx.x];
    __syncthreads();
    int i = blockIdx.x * blockDim.x + threadIdx.x;
    if (i >= n) return;
    vf4 a = zi[2 * (size_t)i], b = zi[2 * (size_t)i + 1];
    a.x = a.x * s[0] + s[8];  a.y = a.y * s[1] + s[9];
    a.z = a.z * s[2] + s[10]; a.w = a.w * s[3] + s[11];
    b.x = b.x * s[4] + s[12]; b.y = b.y * s[5] + s[13];
    b.z = b.z * s[6] + s[14]; b.w = b.w * s[7] + s[15];
    zi[2 * (size_t)i] = a; zi[2 * (size_t)i + 1] = b;
}

// ---------------- E2: z2 stats over CSR + z2 fp16 materialization ----------------
// m1_c = tanh(zi_f_c + s_c*zjR_c)   (shift folded into zi)
// NT on E-sized streams (src2 in, z2h out) to keep zjH table L2-resident
__global__ __launch_bounds__(256, 2) void e_pass2(const int* __restrict__ src2, const uint32* __restrict__ nodeoff,
                                                  const vf4* __restrict__ ziS, const vh8* __restrict__ zjH,
                                                  const float* __restrict__ ss1g,
                                                  const float* __restrict__ w2, const float* __restrict__ b2,
                                                  float* __restrict__ sums2, vh4* __restrict__ z2h, int n) {
    __shared__ float w2l[32];
    __shared__ float b2l[4];
    __shared__ float st[8];
    if (threadIdx.x < 32) w2l[threadIdx.x] = w2[threadIdx.x];
    if (threadIdx.x < 4)  b2l[threadIdx.x] = b2[threadIdx.x];
    if (threadIdx.x < 8)  st[threadIdx.x] = ss1g[threadIdx.x];
    __syncthreads();
    float a[8];
#pragma unroll
    for (int i = 0; i < 8; ++i) a[i] = 0.f;
    int lane = threadIdx.x & 15;
    int gid0 = (blockIdx.x * 256 + threadIdx.x) >> 4;
    int gstride = (gridDim.x * 256) >> 4;
    for (int i = gid0; i < n; i += gstride) {
        uint32 e0 = nodeoff[i], e1 = nodeoff[i + 1];
        vf4 ziA = ziS[2 * (size_t)i], ziB = ziS[2 * (size_t)i + 1];
        float zi8[8] = {ziA.x, ziA.y, ziA.z, ziA.w, ziB.x, ziB.y, ziB.z, ziB.w};
        for (uint32 e = e0 + lane; e < e1; e += 16) {
            int s = __builtin_nontemporal_load(&src2[e]);
            vh8 zjh = zjH[s];
            float m1[8], z2[4];
#pragma unroll
            for (int c = 0; c < 8; ++c)
                m1[c] = ftanh(zi8[c] + st[c] * (float)zjh[c]);
            mat8x4(m1, w2l, b2l, z2);
            a[0] += z2[0]; a[4] += z2[0] * z2[0];
            a[1] += z2[1]; a[5] += z2[1] * z2[1];
            a[2] += z2[2]; a[6] += z2[2] * z2[2];
            a[3] += z2[3]; a[7] += z2[3] * z2[3];
            vh4 pk;
            pk[0] = (s == i) ? (_Float16)__builtin_inff() : (_Float16)z2[0];
            pk[1] = (_Float16)z2[1];
            pk[2] = (_Float16)z2[2];
            pk[3] = (_Float16)z2[3];
            __builtin_nontemporal_store(pk, &z2h[e]);
        }
    }
    block_reduce_atomics<8, 4>(a, sums2);
}

// ---------------- aggregate: stream z2h over CSR; BN2-affine + tanh; no gathers ----------------
__global__ __launch_bounds__(256, 2) void e_aggr_z(const vh4* __restrict__ z2h, const uint32* __restrict__ nodeoff,
                                                   const float* __restrict__ sums2,
                                                   const float* __restrict__ g2, const float* __restrict__ be2,
                                                   float invE,
                                                   float* __restrict__ acc, int n) {
    __shared__ float ss2[8];
    fin_lds(sums2, g2, be2, 4, invE, ss2);
    int lane = threadIdx.x & 15;
    int gid0 = (blockIdx.x * 256 + threadIdx.x) >> 4;
    int gstride = (gridDim.x * 256) >> 4;
    for (int i = gid0; i < n; i += gstride) {
        uint32 e0 = nodeoff[i], e1 = nodeoff[i + 1];
        float a0 = 0.f, a1 = 0.f, a2 = 0.f, a3 = 0.f;
        for (uint32 e = e0 + lane; e < e1; e += 16) {
            vh4 pk = __builtin_nontemporal_load(&z2h[e]);
            float z0 = (float)pk[0];
            if (z0 != __builtin_inff()) {
                a0 += ftanh(z0 * ss2[0] + ss2[4]);
                a1 += ftanh((float)pk[1] * ss2[1] + ss2[5]);
                a2 += ftanh((float)pk[2] * ss2[2] + ss2[6]);
                a3 += ftanh((float)pk[3] * ss2[3] + ss2[7]);
            }
        }
#pragma unroll
        for (int off = 8; off > 0; off >>= 1) {
            a0 += __shfl_down(a0, off, 16);
            a1 += __shfl_down(a1, off, 16);
            a2 += __shfl_down(a2, off, 16);
            a3 += __shfl_down(a3, off, 16);
        }
        if (lane == 0) {
            float* ap = acc + 8 * (size_t)i;
            ap[0] = a0; ap[1] = a1; ap[2] = a2; ap[3] = a3;
            ap[4] = (float)(e1 - e0);
        }
    }
}

// ---------------- fallback edge kernels (round-1 style, used if ws too small) ----------------
__global__ __launch_bounds__(256) void fb_stats1(const int* __restrict__ idx, const float4* __restrict__ h,
                                                 const float* __restrict__ w1, const float* __restrict__ b1,
                                                 float* __restrict__ sums, float* __restrict__ acc, int E_) {
    float a[16];
#pragma unroll
    for (int i = 0; i < 16; ++i) a[i] = 0.f;
    int stride = gridDim.x * blockDim.x;
    for (int e = blockIdx.x * blockDim.x + threadIdx.x; e < E_; e += stride) {
        int s = __builtin_nontemporal_load(idx + e);
        int d = __builtin_nontemporal_load(idx + E_ + e);
        float4 hi = h[d], hj = h[s];
        stats1_edge(hi, hj, w1, b1, a);
        atomicAdd(acc + 8 * (size_t)d + 4, 1.0f);
    }
    block_reduce_atomics<16, 4>(a, sums);
}

__global__ __launch_bounds__(256) void fb_stats2(const int* __restrict__ idx, const float4* __restrict__ h,
                                                 const float* __restrict__ w1, const float* __restrict__ b1,
                                                 const float* __restrict__ ss1,
                                                 const float* __restrict__ w2, const float* __restrict__ b2,
                                                 float* __restrict__ sums2, int E_) {
    float a[8];
#pragma unroll
    for (int i = 0; i < 8; ++i) a[i] = 0.f;
    int stride = gridDim.x * blockDim.x;
    for (int e = blockIdx.x * blockDim.x + threadIdx.x; e < E_; e += stride) {
        int s = __builtin_nontemporal_load(idx + e);
        int d = __builtin_nontemporal_load(idx + E_ + e);
        float4 hi = h[d], hj = h[s];
        stats2_edge(hi, hj, w1, b1, ss1, w2, b2, a);
    }
    block_reduce_atomics<8, 4>(a, sums2);
}

__global__ __launch_bounds__(256) void fb_scatter(const int* __restrict__ idx, const float4* __restrict__ h,
                                                  const float* __restrict__ w1, const float* __restrict__ b1,
                                                  const float* __restrict__ ss1,
                                                  const float* __restrict__ w2, const float* __restrict__ b2,
                                                  const float* __restrict__ ss2,
                                                  float* __restrict__ acc, int E_) {
    int stride = gridDim.x * blockDim.x;
    for (int e = blockIdx.x * blockDim.x + threadIdx.x; e < E_; e += stride) {
        int s = __builtin_nontemporal_load(idx + e);
        int d = __builtin_nontemporal_load(idx + E_ + e);
        float4 hi = h[d], hj = h[s];
        bool zero = (hi.x == hj.x) && (hi.y == hj.y) && (hi.z == hj.z) && (hi.w == hj.w);
        if (zero) continue;
        vf4 q = z2_edge(hi, hj, w1, b1, ss1, w2, b2);
        float m0 = ftanh(q.x * ss2[0] + ss2[4]);
        float m1v = ftanh(q.y * ss2[1] + ss2[5]);
        float m2v = ftanh(q.z * ss2[2] + ss2[6]);
        float m3 = ftanh(q.w * ss2[3] + ss2[7]);
        float* ap = acc + 8 * (size_t)d;
        atomicAdd(ap + 0, m0);
        atomicAdd(ap + 1, m1v);
        atomicAdd(ap + 2, m2v);
        atomicAdd(ap + 3, m3);
    }
}

// ---------------- node update MLP ----------------
__device__ __forceinline__ void load_u(int i, const float4* __restrict__ h,
                                       const float* __restrict__ acc, float* u) {
    float4 hv = h[i];
    const float* ap = acc + 8 * (size_t)i;
    float c = fmaxf(ap[4], 1.0f);
    u[0] = hv.x; u[1] = hv.y; u[2] = hv.z; u[3] = hv.w;
    u[4] = ap[0]; u[5] = ap[1]; u[6] = ap[2] / c; u[7] = ap[3] / c;
}

__global__ __launch_bounds__(256) void n_stats1(const float4* __restrict__ h,
                                                const float* __restrict__ acc,
                                                const float* __restrict__ w, const float* __restrict__ b,
                                                float* __restrict__ sums, int n) {
    float a[16];
#pragma unroll
    for (int i = 0; i < 16; ++i) a[i] = 0.f;
    int stride = gridDim.x * blockDim.x;
    for (int i = blockIdx.x * blockDim.x + threadIdx.x; i < n; i += stride) {
        float u[8], z[8];
        load_u(i, h, acc, u);
        mat8x8(u, w, b, z);
#pragma unroll
        for (int j = 0; j < 8; ++j) { a[j] += z[j]; a[8 + j] += z[j] * z[j]; }
    }
    block_reduce_atomics<16, 4>(a, sums);
}

__global__ __launch_bounds__(256) void n_stats2(const float4* __restrict__ h,
                                                const float* __restrict__ acc,
                                                const float* __restrict__ w1, const float* __restrict__ b1,
                                                const float* __restrict__ sums3,
                                                const float* __restrict__ g3, const float* __restrict__ be3,
                                                float invN,
                                                const float* __restrict__ w2, const float* __restrict__ b2,
                                                float* __restrict__ sums, int n) {
    __shared__ float ss3[16];
    fin_lds(sums3, g3, be3, 8, invN, ss3);
    float a[8];
#pragma unroll
    for (int i = 0; i < 8; ++i) a[i] = 0.f;
    int stride = gridDim.x * blockDim.x;
    for (int i = blockIdx.x * blockDim.x + threadIdx.x; i < n; i += stride) {
        float u[8], z[8], u1[8], z4[4];
        load_u(i, h, acc, u);
        mat8x8(u, w1, b1, z);
#pragma unroll
        for (int j = 0; j < 8; ++j) u1[j] = ftanh(z[j] * ss3[j] + ss3[8 + j]);
        mat8x4(u1, w2, b2, z4);
#pragma unroll
        for (int c = 0; c < 4; ++c) { a[c] += z4[c]; a[4 + c] += z4[c] * z4[c]; }
    }
    block_reduce_atomics<8, 4>(a, sums);
}

__global__ __launch_bounds__(256) void n_final(const float4* __restrict__ h,
                                               const float* __restrict__ acc,
                                               const float* __restrict__ w1, const float* __restrict__ b1,
                                               const float* __restrict__ sums3,
                                               const float* __restrict__ g3, const float* __restrict__ be3,
                                               const float* __restrict__ sums4,
                                               const float* __restrict__ g4, const float* __restrict__ be4,
                                               float invN,
                                               const float* __restrict__ w2, const float* __restrict__ b2,
                                               const float* __restrict__ pw, const float* __restrict__ pb,
                                               float2* __restrict__ out, int n) {
    __shared__ float ss3[16];
    __shared__ float ss4[8];
    fin_lds(sums3, g3, be3, 8, invN, ss3);
    fin_lds(sums4, g4, be4, 4, invN, ss4);
    int stride = gridDim.x * blockDim.x;
    for (int i = blockIdx.x * blockDim.x + threadIdx.x; i < n; i += stride) {
        float u[8], z[8], u1[8], z4[4], u2[4];
        load_u(i, h, acc, u);
        mat8x8(u, w1, b1, z);
#pragma unroll
        for (int j = 0; j < 8; ++j) u1[j] = ftanh(z[j] * ss3[j] + ss3[8 + j]);
        mat8x4(u1, w2, b2, z4);
#pragma unroll
        for (int c = 0; c < 4; ++c) u2[c] = ftanh(z4[c] * ss4[c] + ss4[4 + c]);
        float o0 = pb[0] + u2[0] * pw[0] + u2[1] * pw[2] + u2[2] * pw[4] + u2[3] * pw[6];
        float o1 = pb[1] + u2[0] * pw[1] + u2[1] * pw[3] + u2[2] * pw[5] + u2[3] * pw[7];
        out[i] = make_float2(o0, o1);
    }
}

extern "C" void kernel_launch(void* const* d_in, const int* in_sizes, int n_in,
                              void* d_out, int out_size, void* d_ws, size_t ws_size,
                              hipStream_t stream) {
    const float* pos  = (const float*)d_in[0];
    const float* vel  = (const float*)d_in[1];
    const int*   eidx = (const int*)d_in[2];
    const float* lin_w = (const float*)d_in[3];
    const float* lin_b = (const float*)d_in[4];
    const float* mw1 = (const float*)d_in[5];
    const float* mb1 = (const float*)d_in[6];
    const float* mg1 = (const float*)d_in[7];
    const float* mbe1 = (const float*)d_in[8];
    const float* mw2 = (const float*)d_in[9];
    const float* mb2 = (const float*)d_in[10];
    const float* mg2 = (const float*)d_in[11];
    const float* mbe2 = (const float*)d_in[12];
    const float* uw1 = (const float*)d_in[13];
    const float* ub1 = (const float*)d_in[14];
    const float* ug1 = (const float*)d_in[15];
    const float* ube1 = (const float*)d_in[16];
    const float* uw2 = (const float*)d_in[17];
    const float* ub2 = (const float*)d_in[18];
    const float* ug2 = (const float*)d_in[19];
    const float* ube2 = (const float*)d_in[20];
    const float* pw = (const float*)d_in[21];
    const float* pb = (const float*)d_in[22];

    int n  = in_sizes[0] / 2;
    int E_ = in_sizes[2] / 2;
    float invE = 1.0f / (float)E_;
    float invN = 1.0f / (float)n;

    // ---- workspace layout (bump allocator, 16B aligned) ----
    char* base = (char*)d_ws;
    size_t off = 0;
    auto alloc = [&](size_t bytes) {
        off = (off + 15) & ~(size_t)15;
        void* p = base + off;
        off += bytes;
        return p;
    };
    float4* h       = (float4*)alloc(16 * (size_t)n);                // 4 MB
    float*  acc     = (float*)alloc(32 * (size_t)n);                 // 8 MB
    float*  sums    = (float*)alloc(512);                            // [0..15] s1, [16..23] s2, [24..39] s3, [40..47] s4
    float*  ss      = sums + 64;                                     // fallback scale/shift area
    float*  ss1g    = (float*)alloc(256);                            // BN1 scale/shift (big path)
    uint32* bbase   = (uint32*)alloc(4 * (NB + 1));
    uint32* rowtot  = (uint32*)alloc(4 * NB);
    uint32* cntmat  = (uint32*)alloc(4 * (size_t)NB * GB);           // 0.5 MB
    uint32* nodeoff = (uint32*)alloc(4 * ((size_t)n + 1));           // 1 MB
    vf4*    ziS     = (vf4*)alloc(32 * (size_t)n);                   // 8 MB
    vh8*    zjH     = (vh8*)alloc(16 * (size_t)n);                   // 4 MB (raw fp16)
    int*    src2    = (int*)alloc(4 * (size_t)E_);                   // 32 MB
    uint32* sp      = (uint32*)alloc(4 * (size_t)E_);                // 32 MB (packed)
    vh4*    z2h     = (vh4*)alloc(8 * (size_t)E_);                   // 64 MB (fp16 z2)
    size_t need_sort = off;                                           // ~154 MB

    bool big = (ws_size >= need_sort) && (n < (1 << 23));

    int nblk = (n + 255) / 256;
    int nbuckets = (n + 511) >> 9;
    int T = (E_ + GB - 1) / GB;

    k_h<<<nblk, 256, 0, stream>>>(pos, vel, lin_w, lin_b, h, n);

    if (big) {
        (void)hipMemsetAsync(sums, 0, 256, stream);

        k_zt<<<nblk, 256, 0, stream>>>(h, mw1, mb1, ziS, zjH, n);

        // fused histogram + h-based z1 stats (r24-proven)
        k_cnt<<<GB, 1024, 0, stream>>>(eidx, h, mw1, mb1, cntmat, sums, E_, T);
        k_scanA<<<NB, 256, 0, stream>>>(cntmat, rowtot);
        k_scanB<<<1, 256, 0, stream>>>(rowtot, bbase);

        k_fin<<<1, 64, 0, stream>>>(sums, ss1g, mg1, mbe1, 8, invE);
        k_fold<<<nblk, 256, 0, stream>>>(ziS, ss1g, n);

        k_reorder<<<GB, 1024, 0, stream>>>(eidx, cntmat, bbase, sp, E_, T);
        k_sort2<<<nbuckets, 256, CAP * 4, stream>>>(sp, bbase, rowtot, src2, nodeoff, n);

        e_pass2<<<4096, 256, 0, stream>>>(src2, nodeoff, ziS, zjH, ss1g,
                                          mw2, mb2, sums + 16, z2h, n);

        e_aggr_z<<<4096, 256, 0, stream>>>(z2h, nodeoff, sums + 16, mg2, mbe2, invE, acc, n);

        n_stats1<<<nblk, 256, 0, stream>>>(h, acc, uw1, ub1, sums + 24, n);
        n_stats2<<<nblk, 256, 0, stream>>>(h, acc, uw1, ub1, sums + 24, ug1, ube1, invN,
                                           uw2, ub2, sums + 40, n);
        n_final<<<nblk, 256, 0, stream>>>(h, acc, uw1, ub1, sums + 24, ug1, ube1,
                                          sums + 40, ug2, ube2, invN,
                                          uw2, ub2, pw, pb, (float2*)d_out, n);
    } else {
        (void)hipMemsetAsync(acc, 0, 32 * (size_t)n + 256, stream);

        fb_stats1<<<4096, 256, 0, stream>>>(eidx, h, mw1, mb1, sums, acc, E_);
        k_fin<<<1, 64, 0, stream>>>(sums, ss, mg1, mbe1, 8, invE);

        fb_stats2<<<4096, 256, 0, stream>>>(eidx, h, mw1, mb1, ss, mw2, mb2, sums + 16, E_);
        k_fin<<<1, 64, 0, stream>>>(sums + 16, ss + 16, mg2, mbe2, 4, invE);

        fb_scatter<<<4096, 256, 0, stream>>>(eidx, h, mw1, mb1, ss, mw2, mb2, ss + 16, acc, E_);

        n_stats1<<<nblk, 256, 0, stream>>>(h, acc, uw1, ub1, sums + 24, n);
        n_stats2<<<nblk, 256, 0, stream>>>(h, acc, uw1, ub1, sums + 24, ug1, ube1, invN,
                                           uw2, ub2, sums + 40, n);
        n_final<<<nblk, 256, 0, stream>>>(h, acc, uw1, ub1, sums + 24, ug1, ube1,
                                          sums + 40, ug2, ube2, invN,
                                          uw2, ub2, pw, pb, (float2*)d_out, n);
    }
}

// Round 29
// 427.843 us; speedup vs baseline: 1.0607x; 1.0607x over previous
//
#include <hip/hip_runtime.h>

#define EPSBN 1e-5f
#define NB 512            // buckets (dst >> 9), 512 nodes per bucket
#define GB 256            // blocks for reorder tiles
#define GBC 512           // blocks for cnt (2 half-tiles per reorder tile)
#define CAP 18000         // LDS sort buffer capacity (edges)

typedef float vf4 __attribute__((ext_vector_type(4)));
typedef _Float16 vh8 __attribute__((ext_vector_type(8)));
typedef _Float16 vh4 __attribute__((ext_vector_type(4)));
typedef unsigned int uint32;

// fast tanh: 1 - 2*rcp(exp(2x)+1)
__device__ __forceinline__ float ftanh(float x) {
    float e = __expf(2.0f * x);
    return 1.0f - 2.0f * __builtin_amdgcn_rcpf(e + 1.0f);
}

__device__ __forceinline__ float wave_sum(float v) {
#pragma unroll
    for (int off = 32; off > 0; off >>= 1) v += __shfl_down(v, off);
    return v;
}

__device__ __forceinline__ void z1_of(const float4 hi, const float4 hj,
                                      const float* __restrict__ w, const float* __restrict__ b,
                                      float* z) {
#pragma unroll
    for (int j = 0; j < 8; ++j) {
        z[j] = b[j]
             + hi.x * w[0 * 8 + j] + hi.y * w[1 * 8 + j] + hi.z * w[2 * 8 + j] + hi.w * w[3 * 8 + j]
             + hj.x * w[4 * 8 + j] + hj.y * w[5 * 8 + j] + hj.z * w[6 * 8 + j] + hj.w * w[7 * 8 + j];
    }
}

__device__ __forceinline__ void mat8x4(const float* u, const float* w,
                                       const float* b, float* z) {
#pragma unroll
    for (int c = 0; c < 4; ++c) {
        float t = b[c];
#pragma unroll
        for (int k = 0; k < 8; ++k) t += u[k] * w[k * 4 + c];
        z[c] = t;
    }
}

__device__ __forceinline__ void mat8x8(const float* u, const float* __restrict__ w,
                                       const float* __restrict__ b, float* z) {
#pragma unroll
    for (int j = 0; j < 8; ++j) {
        float t = b[j];
#pragma unroll
        for (int k = 0; k < 8; ++k) t += u[k] * w[k * 8 + j];
        z[j] = t;
    }
}

// block reduction: NV partials per thread, NW waves per block
template <int NV, int NW>
__device__ __forceinline__ void block_reduce_atomics(float* a, float* __restrict__ sums) {
    __shared__ float red[NV * NW];
    int wid = threadIdx.x >> 6, lane = threadIdx.x & 63;
#pragma unroll
    for (int i = 0; i < NV; ++i) {
        float v = wave_sum(a[i]);
        if (lane == 0) red[i * NW + wid] = v;
    }
    __syncthreads();
    if (threadIdx.x < NV) {
        float v = 0.f;
#pragma unroll
        for (int k = 0; k < NW; ++k) v += red[threadIdx.x * NW + k];
        atomicAdd(&sums[threadIdx.x], v);
    }
}

// compute BN scale/shift into LDS from raw sums (all threads; syncs inside)
__device__ __forceinline__ void fin_lds(const float* __restrict__ sums,
                                        const float* __restrict__ g, const float* __restrict__ be,
                                        int d, float inv, float* out) {
    int j = threadIdx.x;
    if (j < d) {
        float mu = sums[j] * inv;
        float var = sums[d + j] * inv - mu * mu;
        float s = g[j] * rsqrtf(var + EPSBN);
        out[j] = s;
        out[d + j] = be[j] - mu * s;
    }
    __syncthreads();
}

// per-edge z1-stats accumulate (h-based)
__device__ __forceinline__ void stats1_edge(float4 hi, float4 hj,
                                            const float* __restrict__ w1, const float* __restrict__ b1,
                                            float* a) {
    float z[8];
    z1_of(hi, hj, w1, b1, z);
#pragma unroll
    for (int j = 0; j < 8; ++j) { a[j] += z[j]; a[8 + j] += z[j] * z[j]; }
}

// h-based z2 (fallback only)
__device__ __forceinline__ vf4 z2_edge(float4 hi, float4 hj,
                                       const float* __restrict__ w1, const float* __restrict__ b1,
                                       const float* ss1,
                                       const float* __restrict__ w2, const float* __restrict__ b2) {
    float z[8], m1[8], z2[4];
    z1_of(hi, hj, w1, b1, z);
#pragma unroll
    for (int j = 0; j < 8; ++j) m1[j] = ftanh(z[j] * ss1[j] + ss1[8 + j]);
    mat8x4(m1, w2, b2, z2);
    vf4 r = {z2[0], z2[1], z2[2], z2[3]};
    return r;
}

__device__ __forceinline__ void stats2_edge(float4 hi, float4 hj,
                                            const float* __restrict__ w1, const float* __restrict__ b1,
                                            const float* ss1,
                                            const float* __restrict__ w2, const float* __restrict__ b2,
                                            float* a) {
    vf4 q = z2_edge(hi, hj, w1, b1, ss1, w2, b2);
    a[0] += q.x; a[4] += q.x * q.x;
    a[1] += q.y; a[5] += q.y * q.y;
    a[2] += q.z; a[6] += q.z * q.z;
    a[3] += q.w; a[7] += q.w * q.w;
}

// ---------------- node input projection ----------------
__global__ __launch_bounds__(256) void k_h(const float* __restrict__ pos, const float* __restrict__ vel,
                                           const float* __restrict__ w, const float* __restrict__ b,
                                           float4* __restrict__ h, int n) {
    int i = blockIdx.x * blockDim.x + threadIdx.x;
    if (i >= n) return;
    float2 p = ((const float2*)pos)[i];
    float2 v = ((const float2*)vel)[i];
    float o[4];
#pragma unroll
    for (int d = 0; d < 4; ++d)
        o[d] = b[d] + p.x * w[0 * 4 + d] + p.y * w[1 * 4 + d] + v.x * w[2 * 4 + d] + v.y * w[3 * 4 + d];
    h[i] = make_float4(o[0], o[1], o[2], o[3]);
}

// ---------------- z-tables: ziR = Wi^T h (fp32), zjR = Wj^T h + b1 (fp16) ----------------
__global__ __launch_bounds__(256) void k_zt(const float4* __restrict__ h,
                                            const float* __restrict__ w1, const float* __restrict__ b1,
                                            vf4* __restrict__ zi, vh8* __restrict__ zjH, int n) {
    int i = blockIdx.x * blockDim.x + threadIdx.x;
    if (i >= n) return;
    float4 hv = h[i];
    float zi8[8];
    vh8 hpk;
#pragma unroll
    for (int j = 0; j < 8; ++j) {
        zi8[j] = hv.x * w1[0 * 8 + j] + hv.y * w1[1 * 8 + j] + hv.z * w1[2 * 8 + j] + hv.w * w1[3 * 8 + j];
        float zj = b1[j]
                 + hv.x * w1[4 * 8 + j] + hv.y * w1[5 * 8 + j] + hv.z * w1[6 * 8 + j] + hv.w * w1[7 * 8 + j];
        hpk[j] = (_Float16)zj;
    }
    vf4 a = {zi8[0], zi8[1], zi8[2], zi8[3]};
    vf4 b_ = {zi8[4], zi8[5], zi8[6], zi8[7]};
    zi[2 * (size_t)i] = a; zi[2 * (size_t)i + 1] = b_;
    zjH[i] = hpk;
}

// ---------------- count + fused h-based z1 stats: GBC half-tiles, 2 blocks/CU ----------------
__global__ __launch_bounds__(1024, 1) void k_cnt(const int* __restrict__ idx, const float4* __restrict__ h,
                                                 const float* __restrict__ w1, const float* __restrict__ b1,
                                                 uint32* __restrict__ cntmat, float* __restrict__ sums,
                                                 int E_, int T) {
    __shared__ uint32 hist[NB];
    for (int b = threadIdx.x; b < NB; b += 1024) hist[b] = 0;
    float a[16];
#pragma unroll
    for (int i = 0; i < 16; ++i) a[i] = 0.f;
    __syncthreads();
    int lo = blockIdx.x * T, hi2 = min(E_, lo + T);
    for (int e0 = lo + 4 * threadIdx.x; e0 < hi2; e0 += 4096) {
        int m = min(4, hi2 - e0);
        if (m == 4) {
            int s0 = __builtin_nontemporal_load(idx + e0);
            int s1 = __builtin_nontemporal_load(idx + e0 + 1);
            int s2 = __builtin_nontemporal_load(idx + e0 + 2);
            int s3 = __builtin_nontemporal_load(idx + e0 + 3);
            int d0 = __builtin_nontemporal_load(idx + E_ + e0);
            int d1 = __builtin_nontemporal_load(idx + E_ + e0 + 1);
            int d2 = __builtin_nontemporal_load(idx + E_ + e0 + 2);
            int d3 = __builtin_nontemporal_load(idx + E_ + e0 + 3);
            float4 hi0 = h[d0], hj0 = h[s0];
            float4 hi1 = h[d1], hj1 = h[s1];
            float4 hi2 = h[d2], hj2 = h[s2];
            float4 hi3 = h[d3], hj3 = h[s3];
            atomicAdd(&hist[d0 >> 9], 1u);
            atomicAdd(&hist[d1 >> 9], 1u);
            atomicAdd(&hist[d2 >> 9], 1u);
            atomicAdd(&hist[d3 >> 9], 1u);
            stats1_edge(hi0, hj0, w1, b1, a);
            stats1_edge(hi1, hj1, w1, b1, a);
            stats1_edge(hi2, hj2, w1, b1, a);
            stats1_edge(hi3, hj3, w1, b1, a);
        } else {
            for (int k = 0; k < m; ++k) {
                int s = __builtin_nontemporal_load(idx + e0 + k);
                int d = __builtin_nontemporal_load(idx + E_ + e0 + k);
                float4 hi = h[d], hj = h[s];
                atomicAdd(&hist[d >> 9], 1u);
                stats1_edge(hi, hj, w1, b1, a);
            }
        }
    }
    __syncthreads();
    for (int b = threadIdx.x; b < NB; b += 1024)
        cntmat[(size_t)b * GBC + blockIdx.x] = hist[b];
    block_reduce_atomics<16, 16>(a, sums);
}

// block-scan of 512 uints (2/thread), exclusive
__device__ __forceinline__ void scan512(uint32* v, uint32* excl_out, uint32* total) {
    __shared__ uint32 ts[256];
    uint32 local = v[0] + v[1];
    ts[threadIdx.x] = local;
    __syncthreads();
    for (int off = 1; off < 256; off <<= 1) {
        uint32 t = (threadIdx.x >= (uint32)off) ? ts[threadIdx.x - off] : 0u;
        __syncthreads();
        ts[threadIdx.x] += t;
        __syncthreads();
    }
    *excl_out = ts[threadIdx.x] - local;
    *total = ts[255];
}

// scan one bucket row of GBC=512 count entries
__global__ __launch_bounds__(256) void k_scanA(uint32* __restrict__ cntmat, uint32* __restrict__ rowtot) {
    size_t base = (size_t)blockIdx.x * GBC + 2 * threadIdx.x;
    uint32 v[2];
    v[0] = cntmat[base]; v[1] = cntmat[base + 1];
    uint32 excl, tot;
    scan512(v, &excl, &tot);
    cntmat[base] = excl;
    cntmat[base + 1] = excl + v[0];
    if (threadIdx.x == 0) rowtot[blockIdx.x] = tot;
}

__global__ __launch_bounds__(256) void k_scanB(const uint32* __restrict__ rowtot, uint32* __restrict__ bbase) {
    uint32 v[2];
    v[0] = rowtot[threadIdx.x * 2]; v[1] = rowtot[threadIdx.x * 2 + 1];
    uint32 excl, tot;
    scan512(v, &excl, &tot);
    bbase[threadIdx.x * 2] = excl;
    bbase[threadIdx.x * 2 + 1] = excl + v[0];
    if (threadIdx.x == 0) bbase[NB] = tot;
}

// ---------------- reorder: packed 4B scatter, 1024-thread blocks, GB tiles ----------------
// tile t covers cnt half-tiles 2t,2t+1; cursor starts at scanned cntmat[b][2t]
__global__ __launch_bounds__(1024, 1) void k_reorder(const int* __restrict__ idx,
                                                     const uint32* __restrict__ cntmat, const uint32* __restrict__ bbase,
                                                     uint32* __restrict__ sp, int E_, int T) {
    __shared__ uint32 cur[NB];
    for (int b = threadIdx.x; b < NB; b += 1024)
        cur[b] = bbase[b] + cntmat[(size_t)b * GBC + 2 * blockIdx.x];
    __syncthreads();
    int lo = blockIdx.x * T, hi2 = min(E_, lo + T);
    for (int e0 = lo + 4 * threadIdx.x; e0 < hi2; e0 += 4096) {
        int m = min(4, hi2 - e0);
        if (m == 4) {
            int s0 = __builtin_nontemporal_load(idx + e0);
            int s1 = __builtin_nontemporal_load(idx + e0 + 1);
            int s2 = __builtin_nontemporal_load(idx + e0 + 2);
            int s3 = __builtin_nontemporal_load(idx + e0 + 3);
            int d0 = __builtin_nontemporal_load(idx + E_ + e0);
            int d1 = __builtin_nontemporal_load(idx + E_ + e0 + 1);
            int d2 = __builtin_nontemporal_load(idx + E_ + e0 + 2);
            int d3 = __builtin_nontemporal_load(idx + E_ + e0 + 3);
            uint32 p0 = atomicAdd(&cur[d0 >> 9], 1u);
            uint32 p1 = atomicAdd(&cur[d1 >> 9], 1u);
            uint32 p2 = atomicAdd(&cur[d2 >> 9], 1u);
            uint32 p3 = atomicAdd(&cur[d3 >> 9], 1u);
            sp[p0] = ((uint32)(d0 & 511) << 23) | (uint32)s0;
            sp[p1] = ((uint32)(d1 & 511) << 23) | (uint32)s1;
            sp[p2] = ((uint32)(d2 & 511) << 23) | (uint32)s2;
            sp[p3] = ((uint32)(d3 & 511) << 23) | (uint32)s3;
        } else {
            for (int k = 0; k < m; ++k) {
                int s = __builtin_nontemporal_load(idx + e0 + k);
                int d = __builtin_nontemporal_load(idx + E_ + e0 + k);
                uint32 pos = atomicAdd(&cur[d >> 9], 1u);
                sp[pos] = ((uint32)(d & 511) << 23) | (uint32)s;
            }
        }
    }
}

// ---------------- sort2: per-bucket counting sort staged in LDS -> CSR ----------------
__global__ __launch_bounds__(256) void k_sort2(const uint32* __restrict__ sp,
                                               const uint32* __restrict__ bbase, const uint32* __restrict__ rowtot,
                                               int* __restrict__ src2, uint32* __restrict__ nodeoff, int n) {
    extern __shared__ uint32 buf[];
    __shared__ uint32 hist[512];
    __shared__ uint32 cur[512];
    int b = blockIdx.x;
    uint32 start = bbase[b];
    uint32 len = rowtot[b];
    uint32 end = start + len;
    hist[threadIdx.x] = 0;
    hist[threadIdx.x + 256] = 0;
    __syncthreads();
    for (uint32 e = start + threadIdx.x; e < end; e += 256) {
        uint32 pk = __builtin_nontemporal_load(&sp[e]);
        atomicAdd(&hist[pk >> 23], 1u);
    }
    __syncthreads();
    uint32 vv[2];
    vv[0] = hist[2 * threadIdx.x];
    vv[1] = hist[2 * threadIdx.x + 1];
    uint32 excl, tot;
    scan512(vv, &excl, &tot);
    cur[2 * threadIdx.x] = excl;
    cur[2 * threadIdx.x + 1] = excl + vv[0];
    int nodebase = b << 9;
    int node0 = nodebase + 2 * threadIdx.x;
    if (node0 <= n)     nodeoff[node0] = start + excl;
    if (node0 + 1 <= n) nodeoff[node0 + 1] = start + excl + vv[0];
    __syncthreads();
    for (uint32 e = start + threadIdx.x; e < end; e += 256) {
        uint32 pk = __builtin_nontemporal_load(&sp[e]);
        uint32 pos = atomicAdd(&cur[pk >> 23], 1u);
        uint32 src = pk & 0x7FFFFFu;
        if (pos < (uint32)CAP) buf[pos] = src;
        else src2[start + pos] = (int)src;
    }
    __syncthreads();
    uint32 lim = min(len, (uint32)CAP);
    for (uint32 k = threadIdx.x; k < lim; k += 256)
        src2[start + k] = (int)buf[k];
}

// ---------------- finalize BN stats -> scale/shift ----------------
__global__ void k_fin(const float* __restrict__ sums, float* __restrict__ ss,
                      const float* __restrict__ g, const float* __restrict__ be,
                      int d, float inv_count) {
    int j = threadIdx.x;
    if (j >= d) return;
    float mu = sums[j] * inv_count;
    float var = sums[d + j] * inv_count - mu * mu;
    float s = g[j] * rsqrtf(var + EPSBN);
    ss[j] = s;
    ss[d + j] = be[j] - mu * s;
}

// ---------------- fold BN1 into zi (zi_f = s * ziR + t) ----------------
__global__ __launch_bounds__(256) void k_fold(vf4* __restrict__ zi, const float* __restrict__ ss1g, int n) {
    __shared__ float s[16];
    if (threadIdx.x < 16) s[threadIdx.x] = ss1g[threadIdx.x];
    __syncthreads();
    int i = blockIdx.x * blockDim.x + threadIdx.x;
    if (i >= n) return;
    vf4 a = zi[2 * (size_t)i], b = zi[2 * (size_t)i + 1];
    a.x = a.x * s[0] + s[8];  a.y = a.y * s[1] + s[9];
    a.z = a.z * s[2] + s[10]; a.w = a.w * s[3] + s[11];
    b.x = b.x * s[4] + s[12]; b.y = b.y * s[5] + s[13];
    b.z = b.z * s[6] + s[14]; b.w = b.w * s[7] + s[15];
    zi[2 * (size_t)i] = a; zi[2 * (size_t)i + 1] = b;
}

// ---------------- E2: z2 stats over CSR + z2 fp16 materialization ----------------
// m1_c = tanh(zi_f_c + s_c*zjR_c)   (shift folded into zi); regular cached accesses
__global__ __launch_bounds__(256, 2) void e_pass2(const int* __restrict__ src2, const uint32* __restrict__ nodeoff,
                                                  const vf4* __restrict__ ziS, const vh8* __restrict__ zjH,
                                                  const float* __restrict__ ss1g,
                                                  const float* __restrict__ w2, const float* __restrict__ b2,
                                                  float* __restrict__ sums2, vh4* __restrict__ z2h, int n) {
    __shared__ float w2l[32];
    __shared__ float b2l[4];
    __shared__ float st[8];
    if (threadIdx.x < 32) w2l[threadIdx.x] = w2[threadIdx.x];
    if (threadIdx.x < 4)  b2l[threadIdx.x] = b2[threadIdx.x];
    if (threadIdx.x < 8)  st[threadIdx.x] = ss1g[threadIdx.x];
    __syncthreads();
    float a[8];
#pragma unroll
    for (int i = 0; i < 8; ++i) a[i] = 0.f;
    int lane = threadIdx.x & 15;
    int gid0 = (blockIdx.x * 256 + threadIdx.x) >> 4;
    int gstride = (gridDim.x * 256) >> 4;
    for (int i = gid0; i < n; i += gstride) {
        uint32 e0 = nodeoff[i], e1 = nodeoff[i + 1];
        vf4 ziA = ziS[2 * (size_t)i], ziB = ziS[2 * (size_t)i + 1];
        float zi8[8] = {ziA.x, ziA.y, ziA.z, ziA.w, ziB.x, ziB.y, ziB.z, ziB.w};
        for (uint32 e = e0 + lane; e < e1; e += 16) {
            int s = src2[e];
            vh8 zjh = zjH[s];
            float m1[8], z2[4];
#pragma unroll
            for (int c = 0; c < 8; ++c)
                m1[c] = ftanh(zi8[c] + st[c] * (float)zjh[c]);
            mat8x4(m1, w2l, b2l, z2);
            a[0] += z2[0]; a[4] += z2[0] * z2[0];
            a[1] += z2[1]; a[5] += z2[1] * z2[1];
            a[2] += z2[2]; a[6] += z2[2] * z2[2];
            a[3] += z2[3]; a[7] += z2[3] * z2[3];
            vh4 pk;
            pk[0] = (s == i) ? (_Float16)__builtin_inff() : (_Float16)z2[0];
            pk[1] = (_Float16)z2[1];
            pk[2] = (_Float16)z2[2];
            pk[3] = (_Float16)z2[3];
            z2h[e] = pk;
        }
    }
    block_reduce_atomics<8, 4>(a, sums2);
}

// ---------------- aggregate: stream z2h over CSR; BN2-affine + tanh; no gathers ----------------
__global__ __launch_bounds__(256, 2) void e_aggr_z(const vh4* __restrict__ z2h, const uint32* __restrict__ nodeoff,
                                                   const float* __restrict__ sums2,
                                                   const float* __restrict__ g2, const float* __restrict__ be2,
                                                   float invE,
                                                   float* __restrict__ acc, int n) {
    __shared__ float ss2[8];
    fin_lds(sums2, g2, be2, 4, invE, ss2);
    int lane = threadIdx.x & 15;
    int gid0 = (blockIdx.x * 256 + threadIdx.x) >> 4;
    int gstride = (gridDim.x * 256) >> 4;
    for (int i = gid0; i < n; i += gstride) {
        uint32 e0 = nodeoff[i], e1 = nodeoff[i + 1];
        float a0 = 0.f, a1 = 0.f, a2 = 0.f, a3 = 0.f;
        for (uint32 e = e0 + lane; e < e1; e += 16) {
            vh4 pk = z2h[e];
            float z0 = (float)pk[0];
            if (z0 != __builtin_inff()) {
                a0 += ftanh(z0 * ss2[0] + ss2[4]);
                a1 += ftanh((float)pk[1] * ss2[1] + ss2[5]);
                a2 += ftanh((float)pk[2] * ss2[2] + ss2[6]);
                a3 += ftanh((float)pk[3] * ss2[3] + ss2[7]);
            }
        }
#pragma unroll
        for (int off = 8; off > 0; off >>= 1) {
            a0 += __shfl_down(a0, off, 16);
            a1 += __shfl_down(a1, off, 16);
            a2 += __shfl_down(a2, off, 16);
            a3 += __shfl_down(a3, off, 16);
        }
        if (lane == 0) {
            float* ap = acc + 8 * (size_t)i;
            ap[0] = a0; ap[1] = a1; ap[2] = a2; ap[3] = a3;
            ap[4] = (float)(e1 - e0);
        }
    }
}

// ---------------- fallback edge kernels (round-1 style, used if ws too small) ----------------
__global__ __launch_bounds__(256) void fb_stats1(const int* __restrict__ idx, const float4* __restrict__ h,
                                                 const float* __restrict__ w1, const float* __restrict__ b1,
                                                 float* __restrict__ sums, float* __restrict__ acc, int E_) {
    float a[16];
#pragma unroll
    for (int i = 0; i < 16; ++i) a[i] = 0.f;
    int stride = gridDim.x * blockDim.x;
    for (int e = blockIdx.x * blockDim.x + threadIdx.x; e < E_; e += stride) {
        int s = __builtin_nontemporal_load(idx + e);
        int d = __builtin_nontemporal_load(idx + E_ + e);
        float4 hi = h[d], hj = h[s];
        stats1_edge(hi, hj, w1, b1, a);
        atomicAdd(acc + 8 * (size_t)d + 4, 1.0f);
    }
    block_reduce_atomics<16, 4>(a, sums);
}

__global__ __launch_bounds__(256) void fb_stats2(const int* __restrict__ idx, const float4* __restrict__ h,
                                                 const float* __restrict__ w1, const float* __restrict__ b1,
                                                 const float* __restrict__ ss1,
                                                 const float* __restrict__ w2, const float* __restrict__ b2,
                                                 float* __restrict__ sums2, int E_) {
    float a[8];
#pragma unroll
    for (int i = 0; i < 8; ++i) a[i] = 0.f;
    int stride = gridDim.x * blockDim.x;
    for (int e = blockIdx.x * blockDim.x + threadIdx.x; e < E_; e += stride) {
        int s = __builtin_nontemporal_load(idx + e);
        int d = __builtin_nontemporal_load(idx + E_ + e);
        float4 hi = h[d], hj = h[s];
        stats2_edge(hi, hj, w1, b1, ss1, w2, b2, a);
    }
    block_reduce_atomics<8, 4>(a, sums2);
}

__global__ __launch_bounds__(256) void fb_scatter(const int* __restrict__ idx, const float4* __restrict__ h,
                                                  const float* __restrict__ w1, const float* __restrict__ b1,
                                                  const float* __restrict__ ss1,
                                                  const float* __restrict__ w2, const float* __restrict__ b2,
                                                  const float* __restrict__ ss2,
                                                  float* __restrict__ acc, int E_) {
    int stride = gridDim.x * blockDim.x;
    for (int e = blockIdx.x * blockDim.x + threadIdx.x; e < E_; e += stride) {
        int s = __builtin_nontemporal_load(idx + e);
        int d = __builtin_nontemporal_load(idx + E_ + e);
        float4 hi = h[d], hj = h[s];
        bool zero = (hi.x == hj.x) && (hi.y == hj.y) && (hi.z == hj.z) && (hi.w == hj.w);
        if (zero) continue;
        vf4 q = z2_edge(hi, hj, w1, b1, ss1, w2, b2);
        float m0 = ftanh(q.x * ss2[0] + ss2[4]);
        float m1v = ftanh(q.y * ss2[1] + ss2[5]);
        float m2v = ftanh(q.z * ss2[2] + ss2[6]);
        float m3 = ftanh(q.w * ss2[3] + ss2[7]);
        float* ap = acc + 8 * (size_t)d;
        atomicAdd(ap + 0, m0);
        atomicAdd(ap + 1, m1v);
        atomicAdd(ap + 2, m2v);
        atomicAdd(ap + 3, m3);
    }
}

// ---------------- node update MLP ----------------
__device__ __forceinline__ void load_u(int i, const float4* __restrict__ h,
                                       const float* __restrict__ acc, float* u) {
    float4 hv = h[i];
    const float* ap = acc + 8 * (size_t)i;
    float c = fmaxf(ap[4], 1.0f);
    u[0] = hv.x; u[1] = hv.y; u[2] = hv.z; u[3] = hv.w;
    u[4] = ap[0]; u[5] = ap[1]; u[6] = ap[2] / c; u[7] = ap[3] / c;
}

__global__ __launch_bounds__(256) void n_stats1(const float4* __restrict__ h,
                                                const float* __restrict__ acc,
                                                const float* __restrict__ w, const float* __restrict__ b,
                                                float* __restrict__ sums, int n) {
    float a[16];
#pragma unroll
    for (int i = 0; i < 16; ++i) a[i] = 0.f;
    int stride = gridDim.x * blockDim.x;
    for (int i = blockIdx.x * blockDim.x + threadIdx.x; i < n; i += stride) {
        float u[8], z[8];
        load_u(i, h, acc, u);
        mat8x8(u, w, b, z);
#pragma unroll
        for (int j = 0; j < 8; ++j) { a[j] += z[j]; a[8 + j] += z[j] * z[j]; }
    }
    block_reduce_atomics<16, 4>(a, sums);
}

__global__ __launch_bounds__(256) void n_stats2(const float4* __restrict__ h,
                                                const float* __restrict__ acc,
                                                const float* __restrict__ w1, const float* __restrict__ b1,
                                                const float* __restrict__ sums3,
                                                const float* __restrict__ g3, const float* __restrict__ be3,
                                                float invN,
                                                const float* __restrict__ w2, const float* __restrict__ b2,
                                                float* __restrict__ sums, int n) {
    __shared__ float ss3[16];
    fin_lds(sums3, g3, be3, 8, invN, ss3);
    float a[8];
#pragma unroll
    for (int i = 0; i < 8; ++i) a[i] = 0.f;
    int stride = gridDim.x * blockDim.x;
    for (int i = blockIdx.x * blockDim.x + threadIdx.x; i < n; i += stride) {
        float u[8], z[8], u1[8], z4[4];
        load_u(i, h, acc, u);
        mat8x8(u, w1, b1, z);
#pragma unroll
        for (int j = 0; j < 8; ++j) u1[j] = ftanh(z[j] * ss3[j] + ss3[8 + j]);
        mat8x4(u1, w2, b2, z4);
#pragma unroll
        for (int c = 0; c < 4; ++c) { a[c] += z4[c]; a[4 + c] += z4[c] * z4[c]; }
    }
    block_reduce_atomics<8, 4>(a, sums);
}

__global__ __launch_bounds__(256) void n_final(const float4* __restrict__ h,
                                               const float* __restrict__ acc,
                                               const float* __restrict__ w1, const float* __restrict__ b1,
                                               const float* __restrict__ sums3,
                                               const float* __restrict__ g3, const float* __restrict__ be3,
                                               const float* __restrict__ sums4,
                                               const float* __restrict__ g4, const float* __restrict__ be4,
                                               float invN,
                                               const float* __restrict__ w2, const float* __restrict__ b2,
                                               const float* __restrict__ pw, const float* __restrict__ pb,
                                               float2* __restrict__ out, int n) {
    __shared__ float ss3[16];
    __shared__ float ss4[8];
    fin_lds(sums3, g3, be3, 8, invN, ss3);
    fin_lds(sums4, g4, be4, 4, invN, ss4);
    int stride = gridDim.x * blockDim.x;
    for (int i = blockIdx.x * blockDim.x + threadIdx.x; i < n; i += stride) {
        float u[8], z[8], u1[8], z4[4], u2[4];
        load_u(i, h, acc, u);
        mat8x8(u, w1, b1, z);
#pragma unroll
        for (int j = 0; j < 8; ++j) u1[j] = ftanh(z[j] * ss3[j] + ss3[8 + j]);
        mat8x4(u1, w2, b2, z4);
#pragma unroll
        for (int c = 0; c < 4; ++c) u2[c] = ftanh(z4[c] * ss4[c] + ss4[4 + c]);
        float o0 = pb[0] + u2[0] * pw[0] + u2[1] * pw[2] + u2[2] * pw[4] + u2[3] * pw[6];
        float o1 = pb[1] + u2[0] * pw[1] + u2[1] * pw[3] + u2[2] * pw[5] + u2[3] * pw[7];
        out[i] = make_float2(o0, o1);
    }
}

extern "C" void kernel_launch(void* const* d_in, const int* in_sizes, int n_in,
                              void* d_out, int out_size, void* d_ws, size_t ws_size,
                              hipStream_t stream) {
    const float* pos  = (const float*)d_in[0];
    const float* vel  = (const float*)d_in[1];
    const int*   eidx = (const int*)d_in[2];
    const float* lin_w = (const float*)d_in[3];
    const float* lin_b = (const float*)d_in[4];
    const float* mw1 = (const float*)d_in[5];
    const float* mb1 = (const float*)d_in[6];
    const float* mg1 = (const float*)d_in[7];
    const float* mbe1 = (const float*)d_in[8];
    const float* mw2 = (const float*)d_in[9];
    const float* mb2 = (const float*)d_in[10];
    const float* mg2 = (const float*)d_in[11];
    const float* mbe2 = (const float*)d_in[12];
    const float* uw1 = (const float*)d_in[13];
    const float* ub1 = (const float*)d_in[14];
    const float* ug1 = (const float*)d_in[15];
    const float* ube1 = (const float*)d_in[16];
    const float* uw2 = (const float*)d_in[17];
    const float* ub2 = (const float*)d_in[18];
    const float* ug2 = (const float*)d_in[19];
    const float* ube2 = (const float*)d_in[20];
    const float* pw = (const float*)d_in[21];
    const float* pb = (const float*)d_in[22];

    int n  = in_sizes[0] / 2;
    int E_ = in_sizes[2] / 2;
    float invE = 1.0f / (float)E_;
    float invN = 1.0f / (float)n;

    // ---- workspace layout (bump allocator, 16B aligned) ----
    char* base = (char*)d_ws;
    size_t off = 0;
    auto alloc = [&](size_t bytes) {
        off = (off + 15) & ~(size_t)15;
        void* p = base + off;
        off += bytes;
        return p;
    };
    float4* h       = (float4*)alloc(16 * (size_t)n);                // 4 MB
    float*  acc     = (float*)alloc(32 * (size_t)n);                 // 8 MB
    float*  sums    = (float*)alloc(512);                            // [0..15] s1, [16..23] s2, [24..39] s3, [40..47] s4
    float*  ss      = sums + 64;                                     // fallback scale/shift area
    float*  ss1g    = (float*)alloc(256);                            // BN1 scale/shift (big path)
    uint32* bbase   = (uint32*)alloc(4 * (NB + 1));
    uint32* rowtot  = (uint32*)alloc(4 * NB);
    uint32* cntmat  = (uint32*)alloc(4 * (size_t)NB * GBC);          // 1 MB
    uint32* nodeoff = (uint32*)alloc(4 * ((size_t)n + 1));           // 1 MB
    vf4*    ziS     = (vf4*)alloc(32 * (size_t)n);                   // 8 MB
    vh8*    zjH     = (vh8*)alloc(16 * (size_t)n);                   // 4 MB (raw fp16)
    int*    src2    = (int*)alloc(4 * (size_t)E_);                   // 32 MB
    uint32* sp      = (uint32*)alloc(4 * (size_t)E_);                // 32 MB (packed)
    vh4*    z2h     = (vh4*)alloc(8 * (size_t)E_);                   // 64 MB (fp16 z2)
    size_t need_sort = off;                                           // ~154 MB

    bool big = (ws_size >= need_sort) && (n < (1 << 23));

    int nblk = (n + 255) / 256;
    int nbuckets = (n + 511) >> 9;
    int TC = (E_ + GBC - 1) / GBC;   // cnt half-tile size
    int TR = 2 * TC;                 // reorder tile = 2 half-tiles

    k_h<<<nblk, 256, 0, stream>>>(pos, vel, lin_w, lin_b, h, n);

    if (big) {
        (void)hipMemsetAsync(sums, 0, 256, stream);

        k_zt<<<nblk, 256, 0, stream>>>(h, mw1, mb1, ziS, zjH, n);

        // fused histogram + h-based z1 stats; 512 blocks -> 2 blocks/CU
        k_cnt<<<GBC, 1024, 0, stream>>>(eidx, h, mw1, mb1, cntmat, sums, E_, TC);
        k_scanA<<<NB, 256, 0, stream>>>(cntmat, rowtot);
        k_scanB<<<1, 256, 0, stream>>>(rowtot, bbase);

        k_fin<<<1, 64, 0, stream>>>(sums, ss1g, mg1, mbe1, 8, invE);
        k_fold<<<nblk, 256, 0, stream>>>(ziS, ss1g, n);

        k_reorder<<<GB, 1024, 0, stream>>>(eidx, cntmat, bbase, sp, E_, TR);
        k_sort2<<<nbuckets, 256, CAP * 4, stream>>>(sp, bbase, rowtot, src2, nodeoff, n);

        e_pass2<<<4096, 256, 0, stream>>>(src2, nodeoff, ziS, zjH, ss1g,
                                          mw2, mb2, sums + 16, z2h, n);

        e_aggr_z<<<4096, 256, 0, stream>>>(z2h, nodeoff, sums + 16, mg2, mbe2, invE, acc, n);

        n_stats1<<<nblk, 256, 0, stream>>>(h, acc, uw1, ub1, sums + 24, n);
        n_stats2<<<nblk, 256, 0, stream>>>(h, acc, uw1, ub1, sums + 24, ug1, ube1, invN,
                                           uw2, ub2, sums + 40, n);
        n_final<<<nblk, 256, 0, stream>>>(h, acc, uw1, ub1, sums + 24, ug1, ube1,
                                          sums + 40, ug2, ube2, invN,
                                          uw2, ub2, pw, pb, (float2*)d_out, n);
    } else {
        (void)hipMemsetAsync(acc, 0, 32 * (size_t)n + 256, stream);

        fb_stats1<<<4096, 256, 0, stream>>>(eidx, h, mw1, mb1, sums, acc, E_);
        k_fin<<<1, 64, 0, stream>>>(sums, ss, mg1, mbe1, 8, invE);

        fb_stats2<<<4096, 256, 0, stream>>>(eidx, h, mw1, mb1, ss, mw2, mb2, sums + 16, E_);
        k_fin<<<1, 64, 0, stream>>>(sums + 16, ss + 16, mg2, mbe2, 4, invE);

        fb_scatter<<<4096, 256, 0, stream>>>(eidx, h, mw1, mb1, ss, mw2, mb2, ss + 16, acc, E_);

        n_stats1<<<nblk, 256, 0, stream>>>(h, acc, uw1, ub1, sums + 24, n);
        n_stats2<<<nblk, 256, 0, stream>>>(h, acc, uw1, ub1, sums + 24, ug1, ube1, invN,
                                           uw2, ub2, sums + 40, n);
        n_final<<<nblk, 256, 0, stream>>>(h, acc, uw1, ub1, sums + 24, ug1, ube1,
                                          sums + 40, ug2, ube2, invN,
                                          uw2, ub2, pw, pb, (float2*)d_out, n);
    }
}

// Round 30
// 414.426 us; speedup vs baseline: 1.0951x; 1.0324x over previous
//
#include <hip/hip_runtime.h>

#define EPSBN 1e-5f
#define NB 512            // buckets (dst >> 9), 512 nodes per bucket
#define GB 256            // blocks for cnt/reorder tiles
#define CAP 18000         // LDS sort buffer capacity (edges)

typedef float vf4 __attribute__((ext_vector_type(4)));
typedef _Float16 vh8 __attribute__((ext_vector_type(8)));
typedef _Float16 vh4 __attribute__((ext_vector_type(4)));
typedef unsigned int uint32;

// fast tanh: 1 - 2*rcp(exp(2x)+1)
__device__ __forceinline__ float ftanh(float x) {
    float e = __expf(2.0f * x);
    return 1.0f - 2.0f * __builtin_amdgcn_rcpf(e + 1.0f);
}

__device__ __forceinline__ float wave_sum(float v) {
#pragma unroll
    for (int off = 32; off > 0; off >>= 1) v += __shfl_down(v, off);
    return v;
}

__device__ __forceinline__ void z1_of(const float4 hi, const float4 hj,
                                      const float* __restrict__ w, const float* __restrict__ b,
                                      float* z) {
#pragma unroll
    for (int j = 0; j < 8; ++j) {
        z[j] = b[j]
             + hi.x * w[0 * 8 + j] + hi.y * w[1 * 8 + j] + hi.z * w[2 * 8 + j] + hi.w * w[3 * 8 + j]
             + hj.x * w[4 * 8 + j] + hj.y * w[5 * 8 + j] + hj.z * w[6 * 8 + j] + hj.w * w[7 * 8 + j];
    }
}

__device__ __forceinline__ void mat8x4(const float* u, const float* w,
                                       const float* b, float* z) {
#pragma unroll
    for (int c = 0; c < 4; ++c) {
        float t = b[c];
#pragma unroll
        for (int k = 0; k < 8; ++k) t += u[k] * w[k * 4 + c];
        z[c] = t;
    }
}

__device__ __forceinline__ void mat8x8(const float* u, const float* __restrict__ w,
                                       const float* __restrict__ b, float* z) {
#pragma unroll
    for (int j = 0; j < 8; ++j) {
        float t = b[j];
#pragma unroll
        for (int k = 0; k < 8; ++k) t += u[k] * w[k * 8 + j];
        z[j] = t;
    }
}

// block reduction: NV partials per thread, NW waves per block
template <int NV, int NW>
__device__ __forceinline__ void block_reduce_atomics(float* a, float* __restrict__ sums) {
    __shared__ float red[NV * NW];
    int wid = threadIdx.x >> 6, lane = threadIdx.x & 63;
#pragma unroll
    for (int i = 0; i < NV; ++i) {
        float v = wave_sum(a[i]);
        if (lane == 0) red[i * NW + wid] = v;
    }
    __syncthreads();
    if (threadIdx.x < NV) {
        float v = 0.f;
#pragma unroll
        for (int k = 0; k < NW; ++k) v += red[threadIdx.x * NW + k];
        atomicAdd(&sums[threadIdx.x], v);
    }
}

// compute BN scale/shift into LDS from raw sums (all threads; syncs inside)
__device__ __forceinline__ void fin_lds(const float* __restrict__ sums,
                                        const float* __restrict__ g, const float* __restrict__ be,
                                        int d, float inv, float* out) {
    int j = threadIdx.x;
    if (j < d) {
        float mu = sums[j] * inv;
        float var = sums[d + j] * inv - mu * mu;
        float s = g[j] * rsqrtf(var + EPSBN);
        out[j] = s;
        out[d + j] = be[j] - mu * s;
    }
    __syncthreads();
}

// per-edge z1-stats accumulate (h-based)
__device__ __forceinline__ void stats1_edge(float4 hi, float4 hj,
                                            const float* __restrict__ w1, const float* __restrict__ b1,
                                            float* a) {
    float z[8];
    z1_of(hi, hj, w1, b1, z);
#pragma unroll
    for (int j = 0; j < 8; ++j) { a[j] += z[j]; a[8 + j] += z[j] * z[j]; }
}

// h-based z2 (fallback only)
__device__ __forceinline__ vf4 z2_edge(float4 hi, float4 hj,
                                       const float* __restrict__ w1, const float* __restrict__ b1,
                                       const float* ss1,
                                       const float* __restrict__ w2, const float* __restrict__ b2) {
    float z[8], m1[8], z2[4];
    z1_of(hi, hj, w1, b1, z);
#pragma unroll
    for (int j = 0; j < 8; ++j) m1[j] = ftanh(z[j] * ss1[j] + ss1[8 + j]);
    mat8x4(m1, w2, b2, z2);
    vf4 r = {z2[0], z2[1], z2[2], z2[3]};
    return r;
}

__device__ __forceinline__ void stats2_edge(float4 hi, float4 hj,
                                            const float* __restrict__ w1, const float* __restrict__ b1,
                                            const float* ss1,
                                            const float* __restrict__ w2, const float* __restrict__ b2,
                                            float* a) {
    vf4 q = z2_edge(hi, hj, w1, b1, ss1, w2, b2);
    a[0] += q.x; a[4] += q.x * q.x;
    a[1] += q.y; a[5] += q.y * q.y;
    a[2] += q.z; a[6] += q.z * q.z;
    a[3] += q.w; a[7] += q.w * q.w;
}

// ---------------- node input projection ----------------
__global__ __launch_bounds__(256) void k_h(const float* __restrict__ pos, const float* __restrict__ vel,
                                           const float* __restrict__ w, const float* __restrict__ b,
                                           float4* __restrict__ h, int n) {
    int i = blockIdx.x * blockDim.x + threadIdx.x;
    if (i >= n) return;
    float2 p = ((const float2*)pos)[i];
    float2 v = ((const float2*)vel)[i];
    float o[4];
#pragma unroll
    for (int d = 0; d < 4; ++d)
        o[d] = b[d] + p.x * w[0 * 4 + d] + p.y * w[1 * 4 + d] + v.x * w[2 * 4 + d] + v.y * w[3 * 4 + d];
    h[i] = make_float4(o[0], o[1], o[2], o[3]);
}

// ---------------- z-tables: ziR = Wi^T h (fp32), zjR = Wj^T h + b1 (fp16) ----------------
__global__ __launch_bounds__(256) void k_zt(const float4* __restrict__ h,
                                            const float* __restrict__ w1, const float* __restrict__ b1,
                                            vf4* __restrict__ zi, vh8* __restrict__ zjH, int n) {
    int i = blockIdx.x * blockDim.x + threadIdx.x;
    if (i >= n) return;
    float4 hv = h[i];
    float zi8[8];
    vh8 hpk;
#pragma unroll
    for (int j = 0; j < 8; ++j) {
        zi8[j] = hv.x * w1[0 * 8 + j] + hv.y * w1[1 * 8 + j] + hv.z * w1[2 * 8 + j] + hv.w * w1[3 * 8 + j];
        float zj = b1[j]
                 + hv.x * w1[4 * 8 + j] + hv.y * w1[5 * 8 + j] + hv.z * w1[6 * 8 + j] + hv.w * w1[7 * 8 + j];
        hpk[j] = (_Float16)zj;
    }
    vf4 a = {zi8[0], zi8[1], zi8[2], zi8[3]};
    vf4 b_ = {zi8[4], zi8[5], zi8[6], zi8[7]};
    zi[2 * (size_t)i] = a; zi[2 * (size_t)i + 1] = b_;
    zjH[i] = hpk;
}

// ---------------- count + fused h-based z1 stats, 1024-thread blocks ----------------
__global__ __launch_bounds__(1024, 1) void k_cnt(const int* __restrict__ idx, const float4* __restrict__ h,
                                                 const float* __restrict__ w1, const float* __restrict__ b1,
                                                 uint32* __restrict__ cntmat, float* __restrict__ sums,
                                                 int E_, int T) {
    __shared__ uint32 hist[NB];
    for (int b = threadIdx.x; b < NB; b += 1024) hist[b] = 0;
    float a[16];
#pragma unroll
    for (int i = 0; i < 16; ++i) a[i] = 0.f;
    __syncthreads();
    int lo = blockIdx.x * T, hi2 = min(E_, lo + T);
    for (int e0 = lo + 4 * threadIdx.x; e0 < hi2; e0 += 4096) {
        int m = min(4, hi2 - e0);
        if (m == 4) {
            int s0 = __builtin_nontemporal_load(idx + e0);
            int s1 = __builtin_nontemporal_load(idx + e0 + 1);
            int s2 = __builtin_nontemporal_load(idx + e0 + 2);
            int s3 = __builtin_nontemporal_load(idx + e0 + 3);
            int d0 = __builtin_nontemporal_load(idx + E_ + e0);
            int d1 = __builtin_nontemporal_load(idx + E_ + e0 + 1);
            int d2 = __builtin_nontemporal_load(idx + E_ + e0 + 2);
            int d3 = __builtin_nontemporal_load(idx + E_ + e0 + 3);
            float4 hi0 = h[d0], hj0 = h[s0];
            float4 hi1 = h[d1], hj1 = h[s1];
            float4 hi2 = h[d2], hj2 = h[s2];
            float4 hi3 = h[d3], hj3 = h[s3];
            atomicAdd(&hist[d0 >> 9], 1u);
            atomicAdd(&hist[d1 >> 9], 1u);
            atomicAdd(&hist[d2 >> 9], 1u);
            atomicAdd(&hist[d3 >> 9], 1u);
            stats1_edge(hi0, hj0, w1, b1, a);
            stats1_edge(hi1, hj1, w1, b1, a);
            stats1_edge(hi2, hj2, w1, b1, a);
            stats1_edge(hi3, hj3, w1, b1, a);
        } else {
            for (int k = 0; k < m; ++k) {
                int s = __builtin_nontemporal_load(idx + e0 + k);
                int d = __builtin_nontemporal_load(idx + E_ + e0 + k);
                float4 hi = h[d], hj = h[s];
                atomicAdd(&hist[d >> 9], 1u);
                stats1_edge(hi, hj, w1, b1, a);
            }
        }
    }
    __syncthreads();
    for (int b = threadIdx.x; b < NB; b += 1024)
        cntmat[(size_t)b * GB + blockIdx.x] = hist[b];
    block_reduce_atomics<16, 16>(a, sums);
}

// block-scan of 256 uints (1/thread), exclusive
__device__ __forceinline__ void scan256(uint32 v, uint32* excl_out, uint32* total) {
    __shared__ uint32 ts[256];
    ts[threadIdx.x] = v;
    __syncthreads();
    for (int off = 1; off < 256; off <<= 1) {
        uint32 t = (threadIdx.x >= (uint32)off) ? ts[threadIdx.x - off] : 0u;
        __syncthreads();
        ts[threadIdx.x] += t;
        __syncthreads();
    }
    *excl_out = ts[threadIdx.x] - v;
    *total = ts[255];
}

// block-scan of 512 uints (2/thread), exclusive
__device__ __forceinline__ void scan512(uint32* v, uint32* excl_out, uint32* total) {
    __shared__ uint32 ts[256];
    uint32 local = v[0] + v[1];
    ts[threadIdx.x] = local;
    __syncthreads();
    for (int off = 1; off < 256; off <<= 1) {
        uint32 t = (threadIdx.x >= (uint32)off) ? ts[threadIdx.x - off] : 0u;
        __syncthreads();
        ts[threadIdx.x] += t;
        __syncthreads();
    }
    *excl_out = ts[threadIdx.x] - local;
    *total = ts[255];
}

__global__ __launch_bounds__(256) void k_scanA(uint32* __restrict__ cntmat, uint32* __restrict__ rowtot) {
    size_t base = (size_t)blockIdx.x * GB + threadIdx.x;
    uint32 v = cntmat[base];
    uint32 excl, tot;
    scan256(v, &excl, &tot);
    cntmat[base] = excl;
    if (threadIdx.x == 0) rowtot[blockIdx.x] = tot;
}

__global__ __launch_bounds__(256) void k_scanB(const uint32* __restrict__ rowtot, uint32* __restrict__ bbase) {
    uint32 v[2];
    v[0] = rowtot[threadIdx.x * 2]; v[1] = rowtot[threadIdx.x * 2 + 1];
    uint32 excl, tot;
    scan512(v, &excl, &tot);
    bbase[threadIdx.x * 2] = excl;
    bbase[threadIdx.x * 2 + 1] = excl + v[0];
    if (threadIdx.x == 0) bbase[NB] = tot;
}

// ---------------- reorder: packed 4B scatter, 1024-thread blocks ----------------
__global__ __launch_bounds__(1024, 1) void k_reorder(const int* __restrict__ idx,
                                                     const uint32* __restrict__ cntmat, const uint32* __restrict__ bbase,
                                                     uint32* __restrict__ sp, int E_, int T) {
    __shared__ uint32 cur[NB];
    for (int b = threadIdx.x; b < NB; b += 1024)
        cur[b] = bbase[b] + cntmat[(size_t)b * GB + blockIdx.x];
    __syncthreads();
    int lo = blockIdx.x * T, hi2 = min(E_, lo + T);
    for (int e0 = lo + 4 * threadIdx.x; e0 < hi2; e0 += 4096) {
        int m = min(4, hi2 - e0);
        if (m == 4) {
            int s0 = __builtin_nontemporal_load(idx + e0);
            int s1 = __builtin_nontemporal_load(idx + e0 + 1);
            int s2 = __builtin_nontemporal_load(idx + e0 + 2);
            int s3 = __builtin_nontemporal_load(idx + e0 + 3);
            int d0 = __builtin_nontemporal_load(idx + E_ + e0);
            int d1 = __builtin_nontemporal_load(idx + E_ + e0 + 1);
            int d2 = __builtin_nontemporal_load(idx + E_ + e0 + 2);
            int d3 = __builtin_nontemporal_load(idx + E_ + e0 + 3);
            uint32 p0 = atomicAdd(&cur[d0 >> 9], 1u);
            uint32 p1 = atomicAdd(&cur[d1 >> 9], 1u);
            uint32 p2 = atomicAdd(&cur[d2 >> 9], 1u);
            uint32 p3 = atomicAdd(&cur[d3 >> 9], 1u);
            sp[p0] = ((uint32)(d0 & 511) << 23) | (uint32)s0;
            sp[p1] = ((uint32)(d1 & 511) << 23) | (uint32)s1;
            sp[p2] = ((uint32)(d2 & 511) << 23) | (uint32)s2;
            sp[p3] = ((uint32)(d3 & 511) << 23) | (uint32)s3;
        } else {
            for (int k = 0; k < m; ++k) {
                int s = __builtin_nontemporal_load(idx + e0 + k);
                int d = __builtin_nontemporal_load(idx + E_ + e0 + k);
                uint32 pos = atomicAdd(&cur[d >> 9], 1u);
                sp[pos] = ((uint32)(d & 511) << 23) | (uint32)s;
            }
        }
    }
}

// ---------------- sort2: per-bucket counting sort staged in LDS -> CSR ----------------
__global__ __launch_bounds__(256) void k_sort2(const uint32* __restrict__ sp,
                                               const uint32* __restrict__ bbase, const uint32* __restrict__ rowtot,
                                               int* __restrict__ src2, uint32* __restrict__ nodeoff, int n) {
    extern __shared__ uint32 buf[];
    __shared__ uint32 hist[512];
    __shared__ uint32 cur[512];
    int b = blockIdx.x;
    uint32 start = bbase[b];
    uint32 len = rowtot[b];
    uint32 end = start + len;
    hist[threadIdx.x] = 0;
    hist[threadIdx.x + 256] = 0;
    __syncthreads();
    for (uint32 e = start + threadIdx.x; e < end; e += 256) {
        uint32 pk = __builtin_nontemporal_load(&sp[e]);
        atomicAdd(&hist[pk >> 23], 1u);
    }
    __syncthreads();
    uint32 vv[2];
    vv[0] = hist[2 * threadIdx.x];
    vv[1] = hist[2 * threadIdx.x + 1];
    uint32 excl, tot;
    scan512(vv, &excl, &tot);
    cur[2 * threadIdx.x] = excl;
    cur[2 * threadIdx.x + 1] = excl + vv[0];
    int nodebase = b << 9;
    int node0 = nodebase + 2 * threadIdx.x;
    if (node0 <= n)     nodeoff[node0] = start + excl;
    if (node0 + 1 <= n) nodeoff[node0 + 1] = start + excl + vv[0];
    __syncthreads();
    for (uint32 e = start + threadIdx.x; e < end; e += 256) {
        uint32 pk = __builtin_nontemporal_load(&sp[e]);
        uint32 pos = atomicAdd(&cur[pk >> 23], 1u);
        uint32 src = pk & 0x7FFFFFu;
        if (pos < (uint32)CAP) buf[pos] = src;
        else src2[start + pos] = (int)src;
    }
    __syncthreads();
    uint32 lim = min(len, (uint32)CAP);
    for (uint32 k = threadIdx.x; k < lim; k += 256)
        src2[start + k] = (int)buf[k];
}

// ---------------- finalize BN stats -> scale/shift ----------------
__global__ void k_fin(const float* __restrict__ sums, float* __restrict__ ss,
                      const float* __restrict__ g, const float* __restrict__ be,
                      int d, float inv_count) {
    int j = threadIdx.x;
    if (j >= d) return;
    float mu = sums[j] * inv_count;
    float var = sums[d + j] * inv_count - mu * mu;
    float s = g[j] * rsqrtf(var + EPSBN);
    ss[j] = s;
    ss[d + j] = be[j] - mu * s;
}

// ---------------- fold BN1 into zi (zi_f = s * ziR + t) ----------------
__global__ __launch_bounds__(256) void k_fold(vf4* __restrict__ zi, const float* __restrict__ ss1g, int n) {
    __shared__ float s[16];
    if (threadIdx.x < 16) s[threadIdx.x] = ss1g[threadIdx.x];
    __syncthreads();
    int i = blockIdx.x * blockDim.x + threadIdx.x;
    if (i >= n) return;
    vf4 a = zi[2 * (size_t)i], b = zi[2 * (size_t)i + 1];
    a.x = a.x * s[0] + s[8];  a.y = a.y * s[1] + s[9];
    a.z = a.z * s[2] + s[10]; a.w = a.w * s[3] + s[11];
    b.x = b.x * s[4] + s[12]; b.y = b.y * s[5] + s[13];
    b.z = b.z * s[6] + s[14]; b.w = b.w * s[7] + s[15];
    zi[2 * (size_t)i] = a; zi[2 * (size_t)i + 1] = b;
}

// ---------------- E2: z2 stats over CSR + z2 fp16 materialization ----------------
// m1_c = tanh(zi_f_c + s_c*zjR_c); unroll-2 edges/lane for 2 independent gather chains
__global__ __launch_bounds__(256, 2) void e_pass2(const int* __restrict__ src2, const uint32* __restrict__ nodeoff,
                                                  const vf4* __restrict__ ziS, const vh8* __restrict__ zjH,
                                                  const float* __restrict__ ss1g,
                                                  const float* __restrict__ w2, const float* __restrict__ b2,
                                                  float* __restrict__ sums2, vh4* __restrict__ z2h, int n) {
    __shared__ float w2l[32];
    __shared__ float b2l[4];
    __shared__ float st[8];
    if (threadIdx.x < 32) w2l[threadIdx.x] = w2[threadIdx.x];
    if (threadIdx.x < 4)  b2l[threadIdx.x] = b2[threadIdx.x];
    if (threadIdx.x < 8)  st[threadIdx.x] = ss1g[threadIdx.x];
    __syncthreads();
    float a[8];
#pragma unroll
    for (int i = 0; i < 8; ++i) a[i] = 0.f;
    int lane = threadIdx.x & 15;
    int gid0 = (blockIdx.x * 256 + threadIdx.x) >> 4;
    int gstride = (gridDim.x * 256) >> 4;
    for (int i = gid0; i < n; i += gstride) {
        uint32 e0 = nodeoff[i], e1 = nodeoff[i + 1];
        vf4 ziA = ziS[2 * (size_t)i], ziB = ziS[2 * (size_t)i + 1];
        float zi8[8] = {ziA.x, ziA.y, ziA.z, ziA.w, ziB.x, ziB.y, ziB.z, ziB.w};
        uint32 e = e0 + lane;
        // double iterations: edges e and e+16 gathered independently
        for (; e + 16 < e1; e += 32) {
            int sA = src2[e];
            int sB = src2[e + 16];
            vh8 ja = zjH[sA];
            vh8 jb = zjH[sB];
            float mA[8], mB[8], zA[4], zB[4];
#pragma unroll
            for (int c = 0; c < 8; ++c) {
                mA[c] = ftanh(zi8[c] + st[c] * (float)ja[c]);
                mB[c] = ftanh(zi8[c] + st[c] * (float)jb[c]);
            }
            mat8x4(mA, w2l, b2l, zA);
            mat8x4(mB, w2l, b2l, zB);
#pragma unroll
            for (int c = 0; c < 4; ++c) {
                a[c] += zA[c] + zB[c];
                a[4 + c] += zA[c] * zA[c] + zB[c] * zB[c];
            }
            vh4 pa, pb2;
            pa[0] = (sA == i) ? (_Float16)__builtin_inff() : (_Float16)zA[0];
            pa[1] = (_Float16)zA[1];
            pa[2] = (_Float16)zA[2];
            pa[3] = (_Float16)zA[3];
            pb2[0] = (sB == i) ? (_Float16)__builtin_inff() : (_Float16)zB[0];
            pb2[1] = (_Float16)zB[1];
            pb2[2] = (_Float16)zB[2];
            pb2[3] = (_Float16)zB[3];
            z2h[e] = pa;
            z2h[e + 16] = pb2;
        }
        if (e < e1) {
            int s = src2[e];
            vh8 zjh = zjH[s];
            float m1[8], z2[4];
#pragma unroll
            for (int c = 0; c < 8; ++c)
                m1[c] = ftanh(zi8[c] + st[c] * (float)zjh[c]);
            mat8x4(m1, w2l, b2l, z2);
#pragma unroll
            for (int c = 0; c < 4; ++c) {
                a[c] += z2[c];
                a[4 + c] += z2[c] * z2[c];
            }
            vh4 pk;
            pk[0] = (s == i) ? (_Float16)__builtin_inff() : (_Float16)z2[0];
            pk[1] = (_Float16)z2[1];
            pk[2] = (_Float16)z2[2];
            pk[3] = (_Float16)z2[3];
            z2h[e] = pk;
        }
    }
    block_reduce_atomics<8, 4>(a, sums2);
}

// ---------------- aggregate: stream z2h over CSR; BN2-affine + tanh; unroll-2 ----------------
__global__ __launch_bounds__(256, 2) void e_aggr_z(const vh4* __restrict__ z2h, const uint32* __restrict__ nodeoff,
                                                   const float* __restrict__ sums2,
                                                   const float* __restrict__ g2, const float* __restrict__ be2,
                                                   float invE,
                                                   float* __restrict__ acc, int n) {
    __shared__ float ss2[8];
    fin_lds(sums2, g2, be2, 4, invE, ss2);
    int lane = threadIdx.x & 15;
    int gid0 = (blockIdx.x * 256 + threadIdx.x) >> 4;
    int gstride = (gridDim.x * 256) >> 4;
    for (int i = gid0; i < n; i += gstride) {
        uint32 e0 = nodeoff[i], e1 = nodeoff[i + 1];
        float a0 = 0.f, a1 = 0.f, a2 = 0.f, a3 = 0.f;
        uint32 e = e0 + lane;
        for (; e + 16 < e1; e += 32) {
            vh4 pa = z2h[e];
            vh4 pb = z2h[e + 16];
            float za = (float)pa[0];
            float zb = (float)pb[0];
            if (za != __builtin_inff()) {
                a0 += ftanh(za * ss2[0] + ss2[4]);
                a1 += ftanh((float)pa[1] * ss2[1] + ss2[5]);
                a2 += ftanh((float)pa[2] * ss2[2] + ss2[6]);
                a3 += ftanh((float)pa[3] * ss2[3] + ss2[7]);
            }
            if (zb != __builtin_inff()) {
                a0 += ftanh(zb * ss2[0] + ss2[4]);
                a1 += ftanh((float)pb[1] * ss2[1] + ss2[5]);
                a2 += ftanh((float)pb[2] * ss2[2] + ss2[6]);
                a3 += ftanh((float)pb[3] * ss2[3] + ss2[7]);
            }
        }
        if (e < e1) {
            vh4 pk = z2h[e];
            float z0 = (float)pk[0];
            if (z0 != __builtin_inff()) {
                a0 += ftanh(z0 * ss2[0] + ss2[4]);
                a1 += ftanh((float)pk[1] * ss2[1] + ss2[5]);
                a2 += ftanh((float)pk[2] * ss2[2] + ss2[6]);
                a3 += ftanh((float)pk[3] * ss2[3] + ss2[7]);
            }
        }
#pragma unroll
        for (int off = 8; off > 0; off >>= 1) {
            a0 += __shfl_down(a0, off, 16);
            a1 += __shfl_down(a1, off, 16);
            a2 += __shfl_down(a2, off, 16);
            a3 += __shfl_down(a3, off, 16);
        }
        if (lane == 0) {
            float* ap = acc + 8 * (size_t)i;
            ap[0] = a0; ap[1] = a1; ap[2] = a2; ap[3] = a3;
            ap[4] = (float)(e1 - e0);
        }
    }
}

// ---------------- fallback edge kernels (round-1 style, used if ws too small) ----------------
__global__ __launch_bounds__(256) void fb_stats1(const int* __restrict__ idx, const float4* __restrict__ h,
                                                 const float* __restrict__ w1, const float* __restrict__ b1,
                                                 float* __restrict__ sums, float* __restrict__ acc, int E_) {
    float a[16];
#pragma unroll
    for (int i = 0; i < 16; ++i) a[i] = 0.f;
    int stride = gridDim.x * blockDim.x;
    for (int e = blockIdx.x * blockDim.x + threadIdx.x; e < E_; e += stride) {
        int s = __builtin_nontemporal_load(idx + e);
        int d = __builtin_nontemporal_load(idx + E_ + e);
        float4 hi = h[d], hj = h[s];
        stats1_edge(hi, hj, w1, b1, a);
        atomicAdd(acc + 8 * (size_t)d + 4, 1.0f);
    }
    block_reduce_atomics<16, 4>(a, sums);
}

__global__ __launch_bounds__(256) void fb_stats2(const int* __restrict__ idx, const float4* __restrict__ h,
                                                 const float* __restrict__ w1, const float* __restrict__ b1,
                                                 const float* __restrict__ ss1,
                                                 const float* __restrict__ w2, const float* __restrict__ b2,
                                                 float* __restrict__ sums2, int E_) {
    float a[8];
#pragma unroll
    for (int i = 0; i < 8; ++i) a[i] = 0.f;
    int stride = gridDim.x * blockDim.x;
    for (int e = blockIdx.x * blockDim.x + threadIdx.x; e < E_; e += stride) {
        int s = __builtin_nontemporal_load(idx + e);
        int d = __builtin_nontemporal_load(idx + E_ + e);
        float4 hi = h[d], hj = h[s];
        stats2_edge(hi, hj, w1, b1, ss1, w2, b2, a);
    }
    block_reduce_atomics<8, 4>(a, sums2);
}

__global__ __launch_bounds__(256) void fb_scatter(const int* __restrict__ idx, const float4* __restrict__ h,
                                                  const float* __restrict__ w1, const float* __restrict__ b1,
                                                  const float* __restrict__ ss1,
                                                  const float* __restrict__ w2, const float* __restrict__ b2,
                                                  const float* __restrict__ ss2,
                                                  float* __restrict__ acc, int E_) {
    int stride = gridDim.x * blockDim.x;
    for (int e = blockIdx.x * blockDim.x + threadIdx.x; e < E_; e += stride) {
        int s = __builtin_nontemporal_load(idx + e);
        int d = __builtin_nontemporal_load(idx + E_ + e);
        float4 hi = h[d], hj = h[s];
        bool zero = (hi.x == hj.x) && (hi.y == hj.y) && (hi.z == hj.z) && (hi.w == hj.w);
        if (zero) continue;
        vf4 q = z2_edge(hi, hj, w1, b1, ss1, w2, b2);
        float m0 = ftanh(q.x * ss2[0] + ss2[4]);
        float m1v = ftanh(q.y * ss2[1] + ss2[5]);
        float m2v = ftanh(q.z * ss2[2] + ss2[6]);
        float m3 = ftanh(q.w * ss2[3] + ss2[7]);
        float* ap = acc + 8 * (size_t)d;
        atomicAdd(ap + 0, m0);
        atomicAdd(ap + 1, m1v);
        atomicAdd(ap + 2, m2v);
        atomicAdd(ap + 3, m3);
    }
}

// ---------------- node update MLP ----------------
__device__ __forceinline__ void load_u(int i, const float4* __restrict__ h,
                                       const float* __restrict__ acc, float* u) {
    float4 hv = h[i];
    const float* ap = acc + 8 * (size_t)i;
    float c = fmaxf(ap[4], 1.0f);
    u[0] = hv.x; u[1] = hv.y; u[2] = hv.z; u[3] = hv.w;
    u[4] = ap[0]; u[5] = ap[1]; u[6] = ap[2] / c; u[7] = ap[3] / c;
}

__global__ __launch_bounds__(256) void n_stats1(const float4* __restrict__ h,
                                                const float* __restrict__ acc,
                                                const float* __restrict__ w, const float* __restrict__ b,
                                                float* __restrict__ sums, int n) {
    float a[16];
#pragma unroll
    for (int i = 0; i < 16; ++i) a[i] = 0.f;
    int stride = gridDim.x * blockDim.x;
    for (int i = blockIdx.x * blockDim.x + threadIdx.x; i < n; i += stride) {
        float u[8], z[8];
        load_u(i, h, acc, u);
        mat8x8(u, w, b, z);
#pragma unroll
        for (int j = 0; j < 8; ++j) { a[j] += z[j]; a[8 + j] += z[j] * z[j]; }
    }
    block_reduce_atomics<16, 4>(a, sums);
}

__global__ __launch_bounds__(256) void n_stats2(const float4* __restrict__ h,
                                                const float* __restrict__ acc,
                                                const float* __restrict__ w1, const float* __restrict__ b1,
                                                const float* __restrict__ sums3,
                                                const float* __restrict__ g3, const float* __restrict__ be3,
                                                float invN,
                                                const float* __restrict__ w2, const float* __restrict__ b2,
                                                float* __restrict__ sums, int n) {
    __shared__ float ss3[16];
    fin_lds(sums3, g3, be3, 8, invN, ss3);
    float a[8];
#pragma unroll
    for (int i = 0; i < 8; ++i) a[i] = 0.f;
    int stride = gridDim.x * blockDim.x;
    for (int i = blockIdx.x * blockDim.x + threadIdx.x; i < n; i += stride) {
        float u[8], z[8], u1[8], z4[4];
        load_u(i, h, acc, u);
        mat8x8(u, w1, b1, z);
#pragma unroll
        for (int j = 0; j < 8; ++j) u1[j] = ftanh(z[j] * ss3[j] + ss3[8 + j]);
        mat8x4(u1, w2, b2, z4);
#pragma unroll
        for (int c = 0; c < 4; ++c) { a[c] += z4[c]; a[4 + c] += z4[c] * z4[c]; }
    }
    block_reduce_atomics<8, 4>(a, sums);
}

__global__ __launch_bounds__(256) void n_final(const float4* __restrict__ h,
                                               const float* __restrict__ acc,
                                               const float* __restrict__ w1, const float* __restrict__ b1,
                                               const float* __restrict__ sums3,
                                               const float* __restrict__ g3, const float* __restrict__ be3,
                                               const float* __restrict__ sums4,
                                               const float* __restrict__ g4, const float* __restrict__ be4,
                                               float invN,
                                               const float* __restrict__ w2, const float* __restrict__ b2,
                                               const float* __restrict__ pw, const float* __restrict__ pb,
                                               float2* __restrict__ out, int n) {
    __shared__ float ss3[16];
    __shared__ float ss4[8];
    fin_lds(sums3, g3, be3, 8, invN, ss3);
    fin_lds(sums4, g4, be4, 4, invN, ss4);
    int stride = gridDim.x * blockDim.x;
    for (int i = blockIdx.x * blockDim.x + threadIdx.x; i < n; i += stride) {
        float u[8], z[8], u1[8], z4[4], u2[4];
        load_u(i, h, acc, u);
        mat8x8(u, w1, b1, z);
#pragma unroll
        for (int j = 0; j < 8; ++j) u1[j] = ftanh(z[j] * ss3[j] + ss3[8 + j]);
        mat8x4(u1, w2, b2, z4);
#pragma unroll
        for (int c = 0; c < 4; ++c) u2[c] = ftanh(z4[c] * ss4[c] + ss4[4 + c]);
        float o0 = pb[0] + u2[0] * pw[0] + u2[1] * pw[2] + u2[2] * pw[4] + u2[3] * pw[6];
        float o1 = pb[1] + u2[0] * pw[1] + u2[1] * pw[3] + u2[2] * pw[5] + u2[3] * pw[7];
        out[i] = make_float2(o0, o1);
    }
}

extern "C" void kernel_launch(void* const* d_in, const int* in_sizes, int n_in,
                              void* d_out, int out_size, void* d_ws, size_t ws_size,
                              hipStream_t stream) {
    const float* pos  = (const float*)d_in[0];
    const float* vel  = (const float*)d_in[1];
    const int*   eidx = (const int*)d_in[2];
    const float* lin_w = (const float*)d_in[3];
    const float* lin_b = (const float*)d_in[4];
    const float* mw1 = (const float*)d_in[5];
    const float* mb1 = (const float*)d_in[6];
    const float* mg1 = (const float*)d_in[7];
    const float* mbe1 = (const float*)d_in[8];
    const float* mw2 = (const float*)d_in[9];
    const float* mb2 = (const float*)d_in[10];
    const float* mg2 = (const float*)d_in[11];
    const float* mbe2 = (const float*)d_in[12];
    const float* uw1 = (const float*)d_in[13];
    const float* ub1 = (const float*)d_in[14];
    const float* ug1 = (const float*)d_in[15];
    const float* ube1 = (const float*)d_in[16];
    const float* uw2 = (const float*)d_in[17];
    const float* ub2 = (const float*)d_in[18];
    const float* ug2 = (const float*)d_in[19];
    const float* ube2 = (const float*)d_in[20];
    const float* pw = (const float*)d_in[21];
    const float* pb = (const float*)d_in[22];

    int n  = in_sizes[0] / 2;
    int E_ = in_sizes[2] / 2;
    float invE = 1.0f / (float)E_;
    float invN = 1.0f / (float)n;

    // ---- workspace layout (bump allocator, 16B aligned) ----
    char* base = (char*)d_ws;
    size_t off = 0;
    auto alloc = [&](size_t bytes) {
        off = (off + 15) & ~(size_t)15;
        void* p = base + off;
        off += bytes;
        return p;
    };
    float4* h       = (float4*)alloc(16 * (size_t)n);                // 4 MB
    float*  acc     = (float*)alloc(32 * (size_t)n);                 // 8 MB
    float*  sums    = (float*)alloc(512);                            // [0..15] s1, [16..23] s2, [24..39] s3, [40..47] s4
    float*  ss      = sums + 64;                                     // fallback scale/shift area
    float*  ss1g    = (float*)alloc(256);                            // BN1 scale/shift (big path)
    uint32* bbase   = (uint32*)alloc(4 * (NB + 1));
    uint32* rowtot  = (uint32*)alloc(4 * NB);
    uint32* cntmat  = (uint32*)alloc(4 * (size_t)NB * GB);           // 0.5 MB
    uint32* nodeoff = (uint32*)alloc(4 * ((size_t)n + 1));           // 1 MB
    vf4*    ziS     = (vf4*)alloc(32 * (size_t)n);                   // 8 MB
    vh8*    zjH     = (vh8*)alloc(16 * (size_t)n);                   // 4 MB (raw fp16)
    int*    src2    = (int*)alloc(4 * (size_t)E_);                   // 32 MB
    uint32* sp      = (uint32*)alloc(4 * (size_t)E_);                // 32 MB (packed)
    vh4*    z2h     = (vh4*)alloc(8 * (size_t)E_);                   // 64 MB (fp16 z2)
    size_t need_sort = off;                                           // ~154 MB

    bool big = (ws_size >= need_sort) && (n < (1 << 23));

    int nblk = (n + 255) / 256;
    int nbuckets = (n + 511) >> 9;
    int T = (E_ + GB - 1) / GB;

    k_h<<<nblk, 256, 0, stream>>>(pos, vel, lin_w, lin_b, h, n);

    if (big) {
        (void)hipMemsetAsync(sums, 0, 256, stream);

        k_zt<<<nblk, 256, 0, stream>>>(h, mw1, mb1, ziS, zjH, n);

        // fused histogram + h-based z1 stats (r24-proven)
        k_cnt<<<GB, 1024, 0, stream>>>(eidx, h, mw1, mb1, cntmat, sums, E_, T);
        k_scanA<<<NB, 256, 0, stream>>>(cntmat, rowtot);
        k_scanB<<<1, 256, 0, stream>>>(rowtot, bbase);

        k_fin<<<1, 64, 0, stream>>>(sums, ss1g, mg1, mbe1, 8, invE);
        k_fold<<<nblk, 256, 0, stream>>>(ziS, ss1g, n);

        k_reorder<<<GB, 1024, 0, stream>>>(eidx, cntmat, bbase, sp, E_, T);
        k_sort2<<<nbuckets, 256, CAP * 4, stream>>>(sp, bbase, rowtot, src2, nodeoff, n);

        e_pass2<<<4096, 256, 0, stream>>>(src2, nodeoff, ziS, zjH, ss1g,
                                          mw2, mb2, sums + 16, z2h, n);

        e_aggr_z<<<4096, 256, 0, stream>>>(z2h, nodeoff, sums + 16, mg2, mbe2, invE, acc, n);

        n_stats1<<<nblk, 256, 0, stream>>>(h, acc, uw1, ub1, sums + 24, n);
        n_stats2<<<nblk, 256, 0, stream>>>(h, acc, uw1, ub1, sums + 24, ug1, ube1, invN,
                                           uw2, ub2, sums + 40, n);
        n_final<<<nblk, 256, 0, stream>>>(h, acc, uw1, ub1, sums + 24, ug1, ube1,
                                          sums + 40, ug2, ube2, invN,
                                          uw2, ub2, pw, pb, (float2*)d_out, n);
    } else {
        (void)hipMemsetAsync(acc, 0, 32 * (size_t)n + 256, stream);

        fb_stats1<<<4096, 256, 0, stream>>>(eidx, h, mw1, mb1, sums, acc, E_);
        k_fin<<<1, 64, 0, stream>>>(sums, ss, mg1, mbe1, 8, invE);

        fb_stats2<<<4096, 256, 0, stream>>>(eidx, h, mw1, mb1, ss, mw2, mb2, sums + 16, E_);
        k_fin<<<1, 64, 0, stream>>>(sums + 16, ss + 16, mg2, mbe2, 4, invE);

        fb_scatter<<<4096, 256, 0, stream>>>(eidx, h, mw1, mb1, ss, mw2, mb2, ss + 16, acc, E_);

        n_stats1<<<nblk, 256, 0, stream>>>(h, acc, uw1, ub1, sums + 24, n);
        n_stats2<<<nblk, 256, 0, stream>>>(h, acc, uw1, ub1, sums + 24, ug1, ube1, invN,
                                           uw2, ub2, sums + 40, n);
        n_final<<<nblk, 256, 0, stream>>>(h, acc, uw1, ub1, sums + 24, ug1, ube1,
                                          sums + 40, ug2, ube2, invN,
                                          uw2, ub2, pw, pb, (float2*)d_out, n);
    }
}